// Round 1
// 670.600 us; speedup vs baseline: 1.8398x; 1.8398x over previous
//
#include <hip/hip_runtime.h>
#include <math.h>

#define SEQ 4096
#define DM  1024

#define BM 128
#define BN 128
#define BK 16
#define PAD 4
#define NCT (SEQ / BN)   // 32 column tiles

union U4 { uint4 u; unsigned short s[8]; };

__device__ __forceinline__ float bf2f(unsigned short u) {
    return __uint_as_float(((unsigned int)u) << 16);
}
__device__ __forceinline__ unsigned short f2bf(float f) {
    unsigned int u = __float_as_uint(f);
    return (unsigned short)((u + 0x7FFFu + ((u >> 16) & 1u)) >> 16);
}

// Decide whether buffer holds packed bf16 (1) or fp32 (0).
__device__ __forceinline__ int detect_bf16(const void* p0) {
    const unsigned int* p = (const unsigned int*)p0;
    int cnt = 0;
    #pragma unroll
    for (int i = 0; i < 64; i++) {
        unsigned int e = (p[i] >> 7) & 0xFFu;
        cnt += (e >= 112u && e <= 140u) ? 1 : 0;
    }
    return cnt >= 48 ? 1 : 0;
}

// load 8 consecutive elements (element index idx, multiple of 8) as fp32
__device__ __forceinline__ void load8(const void* base, size_t idx, int isbf, float* v) {
    if (isbf) {
        U4 t; t.u = *(const uint4*)((const unsigned short*)base + idx);
        #pragma unroll
        for (int q = 0; q < 8; q++) v[q] = bf2f(t.s[q]);
    } else {
        const float* f = (const float*)base + idx;
        float4 a = *(const float4*)f;
        float4 b = *(const float4*)(f + 4);
        v[0] = a.x; v[1] = a.y; v[2] = a.z; v[3] = a.w;
        v[4] = b.x; v[5] = b.y; v[6] = b.z; v[7] = b.w;
    }
}

// ---------------- W2 partial: P[kz][d,n] = scale * sum_{e in chunk kz} wq[d,e]*wk[n,e]
// NT GEMM, M=N=1024, K-chunk = 256, grid (8,8,4) = 256 blocks (1/CU).
__global__ __launch_bounds__(256)
void w2_part_kernel(const void* __restrict__ Wq, const void* __restrict__ Wk,
                    float* __restrict__ P, float scale)
{
    __shared__ float As[BK][BM + PAD];
    __shared__ float Bs[BK][BN + PAD];
    const int isq = detect_bf16(Wq);
    const int isk = detect_bf16(Wk);
    const int t  = threadIdx.x;
    const int bx = blockIdx.x;   // n tile over DM
    const int by = blockIdx.y;   // m tile over DM
    const int kz = blockIdx.z;   // k chunk
    const int tm = t >> 4, tn = t & 15;

    float acc[8][8];
    #pragma unroll
    for (int i = 0; i < 8; i++)
        #pragma unroll
        for (int j = 0; j < 8; j++) acc[i][j] = 0.f;

    const int ar = t >> 1;
    const int ak = (t & 1) * 8;
    const int k0 = kz * (DM / 4);

    for (int kt = k0; kt < k0 + DM / 4; kt += BK) {
        float av[8], bv[8];
        load8(Wq, (size_t)(by * BM + ar) * DM + kt + ak, isq, av);
        load8(Wk, (size_t)(bx * BN + ar) * DM + kt + ak, isk, bv);
        #pragma unroll
        for (int q = 0; q < 8; q++) As[ak + q][ar] = av[q];
        #pragma unroll
        for (int q = 0; q < 8; q++) Bs[ak + q][ar] = bv[q];
        __syncthreads();
        #pragma unroll
        for (int kk = 0; kk < BK; kk++) {
            float a[8], b[8];
            #pragma unroll
            for (int i = 0; i < 8; i++) a[i] = As[kk][tm * 8 + i];
            #pragma unroll
            for (int j = 0; j < 8; j++) b[j] = Bs[kk][tn * 8 + j];
            #pragma unroll
            for (int i = 0; i < 8; i++)
                #pragma unroll
                for (int j = 0; j < 8; j++)
                    acc[i][j] = fmaf(a[i], b[j], acc[i][j]);
        }
        __syncthreads();
    }
    float* base = P + (size_t)kz * DM * DM;
    #pragma unroll
    for (int i = 0; i < 8; i++) {
        float* cp = base + (size_t)(by * BM + tm * 8 + i) * DM + bx * BN + tn * 8;
        #pragma unroll
        for (int j = 0; j < 8; j++) cp[j] = acc[i][j] * scale;
    }
}

// ---------------- W2 = sum of 4 K-chunk partials
__global__ __launch_bounds__(256)
void w2_reduce_kernel(const float* __restrict__ P, float* __restrict__ W2)
{
    const size_t N = (size_t)DM * DM;
    size_t i = ((size_t)blockIdx.x * 256 + threadIdx.x) * 4;
    float4 a = *(const float4*)(P + i);
    float4 b = *(const float4*)(P + N + i);
    float4 c = *(const float4*)(P + 2 * N + i);
    float4 d = *(const float4*)(P + 3 * N + i);
    a.x += b.x + c.x + d.x;
    a.y += b.y + c.y + d.y;
    a.z += b.z + c.z + d.z;
    a.w += b.w + c.w + d.w;
    *(float4*)(W2 + i) = a;
}

// ---------------- QW partials: kz=0 -> QW (ws), kz=1 -> QWp (d_out scratch)
// NN GEMM: A = x (flagged), B = W2 (fp32). Grid (8,32,2) = 512 blocks.
__global__ __launch_bounds__(256)
void qw_part_kernel(const void* __restrict__ X, const float* __restrict__ W2,
                    float* __restrict__ O0, float* __restrict__ O1)
{
    __shared__ float As[BK][BM + PAD];
    __shared__ float Bs[BK][BN + PAD];
    const int isbf = detect_bf16(X);
    const int t  = threadIdx.x;
    const int bx = blockIdx.x;   // n tile over DM
    const int by = blockIdx.y;   // m tile over SEQ
    const int kz = blockIdx.z;   // k chunk (0/1)
    const int tm = t >> 4, tn = t & 15;

    float acc[8][8];
    #pragma unroll
    for (int i = 0; i < 8; i++)
        #pragma unroll
        for (int j = 0; j < 8; j++) acc[i][j] = 0.f;

    const int ar = t >> 1;
    const int ak = (t & 1) * 8;
    const int wr = t >> 4;
    const int wn = (t & 15) * 8;
    const int k0 = kz * (DM / 2);

    for (int kt = k0; kt < k0 + DM / 2; kt += BK) {
        float av[8];
        load8(X, (size_t)(by * BM + ar) * DM + kt + ak, isbf, av);
        #pragma unroll
        for (int q = 0; q < 8; q++) As[ak + q][ar] = av[q];
        const float* wp = W2 + (size_t)(kt + wr) * DM + bx * BN + wn;
        float4 b0 = *(const float4*)wp;
        float4 b1 = *(const float4*)(wp + 4);
        Bs[wr][wn + 0] = b0.x; Bs[wr][wn + 1] = b0.y; Bs[wr][wn + 2] = b0.z; Bs[wr][wn + 3] = b0.w;
        Bs[wr][wn + 4] = b1.x; Bs[wr][wn + 5] = b1.y; Bs[wr][wn + 6] = b1.z; Bs[wr][wn + 7] = b1.w;
        __syncthreads();
        #pragma unroll
        for (int kk = 0; kk < BK; kk++) {
            float a[8], b[8];
            #pragma unroll
            for (int i = 0; i < 8; i++) a[i] = As[kk][tm * 8 + i];
            #pragma unroll
            for (int j = 0; j < 8; j++) b[j] = Bs[kk][tn * 8 + j];
            #pragma unroll
            for (int i = 0; i < 8; i++)
                #pragma unroll
                for (int j = 0; j < 8; j++)
                    acc[i][j] = fmaf(a[i], b[j], acc[i][j]);
        }
        __syncthreads();
    }
    float* O = (kz == 0) ? O0 : O1;
    #pragma unroll
    for (int i = 0; i < 8; i++) {
        float* cp = O + (size_t)(by * BM + tm * 8 + i) * DM + bx * BN + tn * 8;
        #pragma unroll
        for (int j = 0; j < 8; j++) cp[j] = acc[i][j];
    }
}

// ---------------- QW += second partial
__global__ __launch_bounds__(256)
void qw_reduce_kernel(float* __restrict__ QW, const float* __restrict__ P)
{
    size_t i = ((size_t)blockIdx.x * 256 + threadIdx.x) * 4;
    float4 a = *(const float4*)(QW + i);
    float4 b = *(const float4*)(P + i);
    a.x += b.x; a.y += b.y; a.z += b.z; a.w += b.w;
    *(float4*)(QW + i) = a;
}

// ---------------- scores (single pass): S tile, per-(tile,row) max/sumexp partials,
// and P = exp(S - m_tile) stored straight to out (dtype-flagged).
__global__ __launch_bounds__(256)
void scores_kernel(const float* __restrict__ QW, const void* __restrict__ X,
                   float* __restrict__ pm, float* __restrict__ pl,
                   void* __restrict__ out)
{
    __shared__ float As[BK][BM + PAD];
    __shared__ float Bs[BK][BN + PAD];
    __shared__ float red[BM][17];
    __shared__ float rowred[BM];

    const int isbf = detect_bf16(X);
    const int t  = threadIdx.x;
    const int bx = blockIdx.x;   // col tile
    const int by = blockIdx.y;   // row tile
    const int tm = t >> 4, tn = t & 15;

    float acc[8][8];
    #pragma unroll
    for (int i = 0; i < 8; i++)
        #pragma unroll
        for (int j = 0; j < 8; j++) acc[i][j] = 0.f;

    const int ar = t >> 1;
    const int ak = (t & 1) * 8;

    for (int kt = 0; kt < DM; kt += BK) {
        const float* ap = QW + (size_t)(by * BM + ar) * DM + kt + ak;
        float4 a0 = *(const float4*)ap;
        float4 a1 = *(const float4*)(ap + 4);
        As[ak + 0][ar] = a0.x; As[ak + 1][ar] = a0.y; As[ak + 2][ar] = a0.z; As[ak + 3][ar] = a0.w;
        As[ak + 4][ar] = a1.x; As[ak + 5][ar] = a1.y; As[ak + 6][ar] = a1.z; As[ak + 7][ar] = a1.w;
        float bv[8];
        load8(X, (size_t)(bx * BN + ar) * DM + kt + ak, isbf, bv);
        #pragma unroll
        for (int q = 0; q < 8; q++) Bs[ak + q][ar] = bv[q];
        __syncthreads();
        #pragma unroll
        for (int kk = 0; kk < BK; kk++) {
            float a[8], b[8];
            #pragma unroll
            for (int i = 0; i < 8; i++) a[i] = As[kk][tm * 8 + i];
            #pragma unroll
            for (int j = 0; j < 8; j++) b[j] = Bs[kk][tn * 8 + j];
            #pragma unroll
            for (int i = 0; i < 8; i++)
                #pragma unroll
                for (int j = 0; j < 8; j++)
                    acc[i][j] = fmaf(a[i], b[j], acc[i][j]);
        }
        __syncthreads();
    }

    // per-row max within this 128-col tile
    #pragma unroll
    for (int i = 0; i < 8; i++) {
        float m = acc[i][0];
        #pragma unroll
        for (int j = 1; j < 8; j++) m = fmaxf(m, acc[i][j]);
        red[tm * 8 + i][tn] = m;
    }
    __syncthreads();
    if (t < BM) {
        float m = red[t][0];
        #pragma unroll
        for (int q = 1; q < 16; q++) m = fmaxf(m, red[t][q]);
        rowred[t] = m;
    }
    __syncthreads();
    // exp, partial sums, and store P to out
    #pragma unroll
    for (int i = 0; i < 8; i++) {
        const int r = tm * 8 + i;
        const float m = rowred[r];
        float e[8];
        float s = 0.f;
        #pragma unroll
        for (int j = 0; j < 8; j++) { e[j] = __expf(acc[i][j] - m); s += e[j]; }
        red[r][tn] = s;
        const int row = by * BM + r;
        if (isbf) {
            U4 o;
            #pragma unroll
            for (int j = 0; j < 8; j++) o.s[j] = f2bf(e[j]);
            *(uint4*)((unsigned short*)out + (size_t)row * SEQ + bx * BN + tn * 8) = o.u;
        } else {
            float* op = (float*)out + (size_t)row * SEQ + bx * BN + tn * 8;
            float4 o0, o1;
            o0.x = e[0]; o0.y = e[1]; o0.z = e[2]; o0.w = e[3];
            o1.x = e[4]; o1.y = e[5]; o1.z = e[6]; o1.w = e[7];
            *(float4*)op = o0;
            *(float4*)(op + 4) = o1;
        }
    }
    __syncthreads();
    if (t < BM) {
        float s = 0.f;
        #pragma unroll
        for (int q = 0; q < 16; q++) s += red[t][q];
        const int grow = by * BM + t;
        pm[(size_t)bx * SEQ + grow] = rowred[t];
        pl[(size_t)bx * SEQ + grow] = s;
    }
}

// ---------------- global reduce: m,l per row, then overwrite pl with per-(tile,row)
// normalization factor exp(m_tile - m) / l.
__global__ __launch_bounds__(256)
void reduce_kernel(const float* __restrict__ pm, float* __restrict__ pl)
{
    int r = blockIdx.x * 256 + threadIdx.x;
    if (r >= SEQ) return;
    float m = pm[r];
    #pragma unroll
    for (int ti = 1; ti < NCT; ti++) m = fmaxf(m, pm[(size_t)ti * SEQ + r]);
    float l = 0.f;
    #pragma unroll
    for (int ti = 0; ti < NCT; ti++)
        l += pl[(size_t)ti * SEQ + r] * __expf(pm[(size_t)ti * SEQ + r] - m);
    float il = 1.f / l;
    #pragma unroll
    for (int ti = 0; ti < NCT; ti++)
        pl[(size_t)ti * SEQ + r] = __expf(pm[(size_t)ti * SEQ + r] - m) * il;
}

// ---------------- fixup: out *= factor[tile][row]   (memory-bound elementwise)
__global__ __launch_bounds__(256)
void fixup_kernel(const float* __restrict__ F, const void* __restrict__ X,
                  void* __restrict__ out)
{
    const int isbf = detect_bf16(X);
    size_t g = ((size_t)blockIdx.x * 256 + threadIdx.x) * 8;  // element index
    const int row = (int)(g >> 12);            // / SEQ
    const int col = (int)(g & (SEQ - 1));
    const float f = F[(size_t)(col >> 7) * SEQ + row];
    if (isbf) {
        unsigned short* p = (unsigned short*)out + g;
        U4 v; v.u = *(const uint4*)p;
        #pragma unroll
        for (int q = 0; q < 8; q++) v.s[q] = f2bf(bf2f(v.s[q]) * f);
        *(uint4*)p = v.u;
    } else {
        float* p = (float*)out + g;
        float4 a = *(const float4*)p;
        float4 b = *(const float4*)(p + 4);
        a.x *= f; a.y *= f; a.z *= f; a.w *= f;
        b.x *= f; b.y *= f; b.z *= f; b.w *= f;
        *(float4*)p = a;
        *(float4*)(p + 4) = b;
    }
}

extern "C" void kernel_launch(void* const* d_in, const int* in_sizes, int n_in,
                              void* d_out, int out_size, void* d_ws, size_t ws_size,
                              hipStream_t stream)
{
    const void* x  = d_in[0];
    const void* wq = d_in[1];
    const void* wk = d_in[2];
    // d_in[3] (w_v), d_in[4] (out_proj) unused by the reference output.

    // Workspace layout (floats), total ~21 MiB:
    //   [0, 4,194,304)          QW fp32 (SEQ*DM) — transiently aliased by the
    //                           4 W2 K-chunk partials (4 * DM*DM = same 16 MiB),
    //                           which are dead before qw writes QW.
    //   [4,194,304, 5,242,880)  W2 fp32 (DM*DM, 4 MiB)
    //   then pm, pl (NCT*SEQ each)
    // d_out scratch: second QW K-chunk partial (16 MiB fp32), dead before
    // scores_kernel overwrites d_out with P.
    float* ws  = (float*)d_ws;
    float* QW  = ws;
    float* W2p = QW;                               // alias (see above)
    float* W2  = ws + (size_t)SEQ * DM;
    float* pm  = W2 + (size_t)DM * DM;
    float* pl  = pm + (size_t)NCT * SEQ;
    float* QWp = (float*)d_out;                    // 16 MiB scratch in output buffer

    dim3 blk(256);
    // W2 = (1/sqrt(1024)) * wq @ wk^T, split-K=4
    w2_part_kernel<<<dim3(DM / BN, DM / BM, 4), blk, 0, stream>>>(wq, wk, W2p, 0.03125f);
    w2_reduce_kernel<<<dim3(DM * DM / (4 * 256)), blk, 0, stream>>>(W2p, W2);
    // QW = x @ W2, split-K=2 (partials: QW in ws, QWp in d_out)
    qw_part_kernel<<<dim3(DM / BN, SEQ / BM, 2), blk, 0, stream>>>(x, W2, QW, QWp);
    qw_reduce_kernel<<<dim3(SEQ * DM / (4 * 256)), blk, 0, stream>>>(QW, QWp);
    // single scores pass: S = QW @ x^T, store P = exp(S - m_tile), partials pm/pl
    scores_kernel<<<dim3(SEQ / BN, SEQ / BM), blk, 0, stream>>>(QW, x, pm, pl, d_out);
    // per-row global max/sum -> per-(tile,row) factors (into pl)
    reduce_kernel<<<dim3(SEQ / 256), blk, 0, stream>>>(pm, pl);
    // out *= factor
    fixup_kernel<<<dim3(SEQ * SEQ / (8 * 256)), blk, 0, stream>>>(pl, x, d_out);
}

// Round 2
// 394.364 us; speedup vs baseline: 3.1286x; 1.7005x over previous
//
#include <hip/hip_runtime.h>
#include <math.h>

#define SEQ 4096
#define DM  1024

#define BM 128
#define BN 128
#define BK 16
#define PAD 4
#define NCT (SEQ / BN)   // 32 column tiles
#define KS 32            // K per MFMA step in scores kernel

typedef __attribute__((ext_vector_type(8))) short bf16x8;
typedef __attribute__((ext_vector_type(4))) float f32x4;

union U4 { uint4 u; unsigned short s[8]; };

__device__ __forceinline__ float bf2f(unsigned short u) {
    return __uint_as_float(((unsigned int)u) << 16);
}
__device__ __forceinline__ unsigned short f2bf(float f) {
    unsigned int u = __float_as_uint(f);
    return (unsigned short)((u + 0x7FFFu + ((u >> 16) & 1u)) >> 16);
}

// Decide whether buffer holds packed bf16 (1) or fp32 (0).
__device__ __forceinline__ int detect_bf16(const void* p0) {
    const unsigned int* p = (const unsigned int*)p0;
    int cnt = 0;
    #pragma unroll
    for (int i = 0; i < 64; i++) {
        unsigned int e = (p[i] >> 7) & 0xFFu;
        cnt += (e >= 112u && e <= 140u) ? 1 : 0;
    }
    return cnt >= 48 ? 1 : 0;
}

// load 8 consecutive elements (element index idx, multiple of 8) as fp32
__device__ __forceinline__ void load8(const void* base, size_t idx, int isbf, float* v) {
    if (isbf) {
        U4 t; t.u = *(const uint4*)((const unsigned short*)base + idx);
        #pragma unroll
        for (int q = 0; q < 8; q++) v[q] = bf2f(t.s[q]);
    } else {
        const float* f = (const float*)base + idx;
        float4 a = *(const float4*)f;
        float4 b = *(const float4*)(f + 4);
        v[0] = a.x; v[1] = a.y; v[2] = a.z; v[3] = a.w;
        v[4] = b.x; v[5] = b.y; v[6] = b.z; v[7] = b.w;
    }
}

// async global -> LDS, 16 bytes per lane (linear LDS dest: base + lane*16)
__device__ __forceinline__ void gl16(const void* g, void* l) {
    __builtin_amdgcn_global_load_lds(
        (const __attribute__((address_space(1))) unsigned int*)g,
        (__attribute__((address_space(3))) unsigned int*)l, 16, 0, 0);
}

// ---------------- W2 partial: P[kz][d,n] = scale * sum_{e in chunk kz} wq[d,e]*wk[n,e]
__global__ __launch_bounds__(256)
void w2_part_kernel(const void* __restrict__ Wq, const void* __restrict__ Wk,
                    float* __restrict__ P, float scale)
{
    __shared__ float As[BK][BM + PAD];
    __shared__ float Bs[BK][BN + PAD];
    const int isq = detect_bf16(Wq);
    const int isk = detect_bf16(Wk);
    const int t  = threadIdx.x;
    const int bx = blockIdx.x;
    const int by = blockIdx.y;
    const int kz = blockIdx.z;
    const int tm = t >> 4, tn = t & 15;

    float acc[8][8];
    #pragma unroll
    for (int i = 0; i < 8; i++)
        #pragma unroll
        for (int j = 0; j < 8; j++) acc[i][j] = 0.f;

    const int ar = t >> 1;
    const int ak = (t & 1) * 8;
    const int k0 = kz * (DM / 4);

    for (int kt = k0; kt < k0 + DM / 4; kt += BK) {
        float av[8], bv[8];
        load8(Wq, (size_t)(by * BM + ar) * DM + kt + ak, isq, av);
        load8(Wk, (size_t)(bx * BN + ar) * DM + kt + ak, isk, bv);
        #pragma unroll
        for (int q = 0; q < 8; q++) As[ak + q][ar] = av[q];
        #pragma unroll
        for (int q = 0; q < 8; q++) Bs[ak + q][ar] = bv[q];
        __syncthreads();
        #pragma unroll
        for (int kk = 0; kk < BK; kk++) {
            float a[8], b[8];
            #pragma unroll
            for (int i = 0; i < 8; i++) a[i] = As[kk][tm * 8 + i];
            #pragma unroll
            for (int j = 0; j < 8; j++) b[j] = Bs[kk][tn * 8 + j];
            #pragma unroll
            for (int i = 0; i < 8; i++)
                #pragma unroll
                for (int j = 0; j < 8; j++)
                    acc[i][j] = fmaf(a[i], b[j], acc[i][j]);
        }
        __syncthreads();
    }
    float* base = P + (size_t)kz * DM * DM;
    #pragma unroll
    for (int i = 0; i < 8; i++) {
        float* cp = base + (size_t)(by * BM + tm * 8 + i) * DM + bx * BN + tn * 8;
        #pragma unroll
        for (int j = 0; j < 8; j++) cp[j] = acc[i][j] * scale;
    }
}

// ---------------- W2 = sum of 4 K-chunk partials
__global__ __launch_bounds__(256)
void w2_reduce_kernel(const float* __restrict__ P, float* __restrict__ W2)
{
    const size_t N = (size_t)DM * DM;
    size_t i = ((size_t)blockIdx.x * 256 + threadIdx.x) * 4;
    float4 a = *(const float4*)(P + i);
    float4 b = *(const float4*)(P + N + i);
    float4 c = *(const float4*)(P + 2 * N + i);
    float4 d = *(const float4*)(P + 3 * N + i);
    a.x += b.x + c.x + d.x;
    a.y += b.y + c.y + d.y;
    a.z += b.z + c.z + d.z;
    a.w += b.w + c.w + d.w;
    *(float4*)(W2 + i) = a;
}

// ---------------- QW partials: kz=0 -> O0 (ws), kz=1 -> O1 (d_out scratch)
__global__ __launch_bounds__(256)
void qw_part_kernel(const void* __restrict__ X, const float* __restrict__ W2,
                    float* __restrict__ O0, float* __restrict__ O1)
{
    __shared__ float As[BK][BM + PAD];
    __shared__ float Bs[BK][BN + PAD];
    const int isbf = detect_bf16(X);
    const int t  = threadIdx.x;
    const int bx = blockIdx.x;
    const int by = blockIdx.y;
    const int kz = blockIdx.z;
    const int tm = t >> 4, tn = t & 15;

    float acc[8][8];
    #pragma unroll
    for (int i = 0; i < 8; i++)
        #pragma unroll
        for (int j = 0; j < 8; j++) acc[i][j] = 0.f;

    const int ar = t >> 1;
    const int ak = (t & 1) * 8;
    const int wr = t >> 4;
    const int wn = (t & 15) * 8;
    const int k0 = kz * (DM / 2);

    for (int kt = k0; kt < k0 + DM / 2; kt += BK) {
        float av[8];
        load8(X, (size_t)(by * BM + ar) * DM + kt + ak, isbf, av);
        #pragma unroll
        for (int q = 0; q < 8; q++) As[ak + q][ar] = av[q];
        const float* wp = W2 + (size_t)(kt + wr) * DM + bx * BN + wn;
        float4 b0 = *(const float4*)wp;
        float4 b1 = *(const float4*)(wp + 4);
        Bs[wr][wn + 0] = b0.x; Bs[wr][wn + 1] = b0.y; Bs[wr][wn + 2] = b0.z; Bs[wr][wn + 3] = b0.w;
        Bs[wr][wn + 4] = b1.x; Bs[wr][wn + 5] = b1.y; Bs[wr][wn + 6] = b1.z; Bs[wr][wn + 7] = b1.w;
        __syncthreads();
        #pragma unroll
        for (int kk = 0; kk < BK; kk++) {
            float a[8], b[8];
            #pragma unroll
            for (int i = 0; i < 8; i++) a[i] = As[kk][tm * 8 + i];
            #pragma unroll
            for (int j = 0; j < 8; j++) b[j] = Bs[kk][tn * 8 + j];
            #pragma unroll
            for (int i = 0; i < 8; i++)
                #pragma unroll
                for (int j = 0; j < 8; j++)
                    acc[i][j] = fmaf(a[i], b[j], acc[i][j]);
        }
        __syncthreads();
    }
    float* O = (kz == 0) ? O0 : O1;
    #pragma unroll
    for (int i = 0; i < 8; i++) {
        float* cp = O + (size_t)(by * BM + tm * 8 + i) * DM + bx * BN + tn * 8;
        #pragma unroll
        for (int j = 0; j < 8; j++) cp[j] = acc[i][j];
    }
}

// ---------------- QW = P0 + P1, split into bf16 hi/lo pair (for MFMA A operand)
__global__ __launch_bounds__(256)
void qw_reduce_split_kernel(const float* __restrict__ P0, const float* __restrict__ P1,
                            unsigned short* __restrict__ Hi, unsigned short* __restrict__ Lo)
{
    size_t i = ((size_t)blockIdx.x * 256 + threadIdx.x) * 8;
    float4 a0 = *(const float4*)(P0 + i);
    float4 a1 = *(const float4*)(P0 + i + 4);
    float4 b0 = *(const float4*)(P1 + i);
    float4 b1 = *(const float4*)(P1 + i + 4);
    float v[8] = {a0.x + b0.x, a0.y + b0.y, a0.z + b0.z, a0.w + b0.w,
                  a1.x + b1.x, a1.y + b1.y, a1.z + b1.z, a1.w + b1.w};
    U4 h, l;
    #pragma unroll
    for (int q = 0; q < 8; q++) {
        h.s[q] = f2bf(v[q]);
        l.s[q] = f2bf(v[q] - bf2f(h.s[q]));
    }
    *(uint4*)(Hi + i) = h.u;
    *(uint4*)(Lo + i) = l.u;
}

// ---------------- scores via MFMA: S = (QWhi+QWlo) @ X^T, fused softmax partials.
// 128x128 tile, 4 waves, mfma_f32_16x16x32_bf16, split-bf16 A for fp32 accuracy.
// LDS tiles are [128][32] bf16 (64B rows) with 16B-chunk XOR swizzle
// (chunk ^= (row>>1)&3) applied on the GLOBAL source (linear LDS dest, rule #21)
// and on the ds_read address -> ~2-way bank aliasing (free).
__global__ __launch_bounds__(256)
void scores_mfma_kernel(const unsigned short* __restrict__ QWhi,
                        const unsigned short* __restrict__ QWlo,
                        const void* __restrict__ X,
                        float* __restrict__ pm, float* __restrict__ pl,
                        void* __restrict__ out)
{
    __shared__ unsigned short lAhi[128 * KS];
    __shared__ unsigned short lAlo[128 * KS];
    __shared__ unsigned short lBhi[128 * KS];
    __shared__ unsigned short lBlo[128 * KS];
    __shared__ float smax[128][2];
    __shared__ float ssum[128][2];

    const int isbf = detect_bf16(X);
    const int t    = threadIdx.x;
    const int bx   = blockIdx.x;   // col tile
    const int by   = blockIdx.y;   // row tile
    const int lane = t & 63;
    const int w    = t >> 6;
    const int wr   = w >> 1;       // wave row (0/1): rows wr*64..+63
    const int wc   = w & 1;        // wave col (0/1): cols wc*64..+63
    const int fr   = lane & 15;    // fragment row/col index
    const int fq   = lane >> 4;    // k-chunk selector (0..3)

    f32x4 acc[4][4];
    #pragma unroll
    for (int i = 0; i < 4; i++)
        #pragma unroll
        for (int j = 0; j < 4; j++)
            acc[i][j] = (f32x4){0.f, 0.f, 0.f, 0.f};

    const int trow = t >> 2;   // staging row (+p*64)
    const int tcs  = t & 3;    // staging chunk slot

    for (int kt = 0; kt < DM; kt += KS) {
        #pragma unroll
        for (int p = 0; p < 2; p++) {
            const int row = p * 64 + trow;
            const int sc  = tcs ^ ((row >> 1) & 3);     // inverse-swizzled source chunk
            const int lof = (p * 256 + t) * 16;         // linear LDS byte offset
            const size_t ga = (size_t)(by * BM + row) * DM + kt + sc * 8;
            gl16(QWhi + ga, (char*)lAhi + lof);
            gl16(QWlo + ga, (char*)lAlo + lof);
            if (isbf) {
                const size_t gb = (size_t)(bx * BN + row) * DM + kt + sc * 8;
                gl16((const unsigned short*)X + gb, (char*)lBhi + lof);
            }
        }
        if (!isbf) {
            // slow path: reg-stage fp32 X, split to hi/lo bf16, swizzled ds_write
            const int row  = t >> 1;
            const int half = t & 1;
            const float* xp = (const float*)X + (size_t)(bx * BN + row) * DM + kt + half * 16;
            float4 v0 = ((const float4*)xp)[0];
            float4 v1 = ((const float4*)xp)[1];
            float4 v2 = ((const float4*)xp)[2];
            float4 v3 = ((const float4*)xp)[3];
            float vv[16] = {v0.x, v0.y, v0.z, v0.w, v1.x, v1.y, v1.z, v1.w,
                            v2.x, v2.y, v2.z, v2.w, v3.x, v3.y, v3.z, v3.w};
            U4 h0, h1, l0, l1;
            #pragma unroll
            for (int q = 0; q < 8; q++) {
                h0.s[q] = f2bf(vv[q]);
                l0.s[q] = f2bf(vv[q] - bf2f(h0.s[q]));
                h1.s[q] = f2bf(vv[8 + q]);
                l1.s[q] = f2bf(vv[8 + q] - bf2f(h1.s[q]));
            }
            const int s  = (row >> 1) & 3;
            const int ca = (2 * half) ^ s;
            const int cb = (2 * half + 1) ^ s;
            *(uint4*)&lBhi[row * KS + ca * 8] = h0.u;
            *(uint4*)&lBhi[row * KS + cb * 8] = h1.u;
            *(uint4*)&lBlo[row * KS + ca * 8] = l0.u;
            *(uint4*)&lBlo[row * KS + cb * 8] = l1.u;
        }
        __syncthreads();

        bf16x8 bh[4];
        #pragma unroll
        for (int nj = 0; nj < 4; nj++) {
            const int br = wc * 64 + nj * 16 + fr;
            const int bc = fq ^ ((br >> 1) & 3);
            bh[nj] = *(const bf16x8*)&lBhi[br * KS + bc * 8];
        }
        #pragma unroll
        for (int mi = 0; mi < 4; mi++) {
            const int ar_ = wr * 64 + mi * 16 + fr;
            const int ac_ = fq ^ ((ar_ >> 1) & 3);
            bf16x8 ah = *(const bf16x8*)&lAhi[ar_ * KS + ac_ * 8];
            bf16x8 al = *(const bf16x8*)&lAlo[ar_ * KS + ac_ * 8];
            #pragma unroll
            for (int nj = 0; nj < 4; nj++) {
                acc[mi][nj] = __builtin_amdgcn_mfma_f32_16x16x32_bf16(ah, bh[nj], acc[mi][nj], 0, 0, 0);
                acc[mi][nj] = __builtin_amdgcn_mfma_f32_16x16x32_bf16(al, bh[nj], acc[mi][nj], 0, 0, 0);
            }
        }
        if (!isbf) {
            bf16x8 bl[4];
            #pragma unroll
            for (int nj = 0; nj < 4; nj++) {
                const int br = wc * 64 + nj * 16 + fr;
                const int bc = fq ^ ((br >> 1) & 3);
                bl[nj] = *(const bf16x8*)&lBlo[br * KS + bc * 8];
            }
            #pragma unroll
            for (int mi = 0; mi < 4; mi++) {
                const int ar_ = wr * 64 + mi * 16 + fr;
                const int ac_ = fq ^ ((ar_ >> 1) & 3);
                bf16x8 ah = *(const bf16x8*)&lAhi[ar_ * KS + ac_ * 8];
                #pragma unroll
                for (int nj = 0; nj < 4; nj++)
                    acc[mi][nj] = __builtin_amdgcn_mfma_f32_16x16x32_bf16(ah, bl[nj], acc[mi][nj], 0, 0, 0);
            }
        }
        __syncthreads();
    }

    // ---- fused softmax epilogue ----
    // C/D layout: col = lane&15 (fr), row = (lane>>4)*4 + reg  [m89/m91-verified]
    float rmx[4][4];
    #pragma unroll
    for (int mi = 0; mi < 4; mi++)
        #pragma unroll
        for (int reg = 0; reg < 4; reg++) {
            float m = acc[mi][0][reg];
            #pragma unroll
            for (int nj = 1; nj < 4; nj++) m = fmaxf(m, acc[mi][nj][reg]);
            m = fmaxf(m, __shfl_xor(m, 1, 64));
            m = fmaxf(m, __shfl_xor(m, 2, 64));
            m = fmaxf(m, __shfl_xor(m, 4, 64));
            m = fmaxf(m, __shfl_xor(m, 8, 64));
            rmx[mi][reg] = m;
        }
    if (fr == 0) {
        #pragma unroll
        for (int mi = 0; mi < 4; mi++)
            #pragma unroll
            for (int reg = 0; reg < 4; reg++)
                smax[wr * 64 + mi * 16 + fq * 4 + reg][wc] = rmx[mi][reg];
    }
    __syncthreads();
    float mt[4][4];
    #pragma unroll
    for (int mi = 0; mi < 4; mi++)
        #pragma unroll
        for (int reg = 0; reg < 4; reg++) {
            const int r = wr * 64 + mi * 16 + fq * 4 + reg;
            mt[mi][reg] = fmaxf(smax[r][0], smax[r][1]);
        }
    float rsm[4][4];
    #pragma unroll
    for (int mi = 0; mi < 4; mi++)
        #pragma unroll
        for (int reg = 0; reg < 4; reg++) rsm[mi][reg] = 0.f;
    #pragma unroll
    for (int mi = 0; mi < 4; mi++)
        #pragma unroll
        for (int nj = 0; nj < 4; nj++)
            #pragma unroll
            for (int reg = 0; reg < 4; reg++) {
                float e = __expf(acc[mi][nj][reg] - mt[mi][reg]);
                acc[mi][nj][reg] = e;
                rsm[mi][reg] += e;
            }
    #pragma unroll
    for (int mi = 0; mi < 4; mi++)
        #pragma unroll
        for (int reg = 0; reg < 4; reg++) {
            float s = rsm[mi][reg];
            s += __shfl_xor(s, 1, 64);
            s += __shfl_xor(s, 2, 64);
            s += __shfl_xor(s, 4, 64);
            s += __shfl_xor(s, 8, 64);
            if (fr == 0) ssum[wr * 64 + mi * 16 + fq * 4 + reg][wc] = s;
        }
    // store P = exp(S - m_tile)
    #pragma unroll
    for (int mi = 0; mi < 4; mi++)
        #pragma unroll
        for (int reg = 0; reg < 4; reg++) {
            const int row = by * BM + wr * 64 + mi * 16 + fq * 4 + reg;
            #pragma unroll
            for (int nj = 0; nj < 4; nj++) {
                const int col = bx * BN + wc * 64 + nj * 16 + fr;
                const float v = acc[mi][nj][reg];
                if (isbf)
                    ((unsigned short*)out)[(size_t)row * SEQ + col] = f2bf(v);
                else
                    ((float*)out)[(size_t)row * SEQ + col] = v;
            }
        }
    __syncthreads();
    if (t < 128) {
        const int grow = by * BM + t;
        pm[(size_t)bx * SEQ + grow] = fmaxf(smax[t][0], smax[t][1]);
        pl[(size_t)bx * SEQ + grow] = ssum[t][0] + ssum[t][1];
    }
}

// ---------------- global reduce: m,l per row -> per-(tile,row) factor exp(m_t - m)/l
__global__ __launch_bounds__(256)
void reduce_kernel(const float* __restrict__ pm, float* __restrict__ pl)
{
    int r = blockIdx.x * 256 + threadIdx.x;
    if (r >= SEQ) return;
    float m = pm[r];
    #pragma unroll
    for (int ti = 1; ti < NCT; ti++) m = fmaxf(m, pm[(size_t)ti * SEQ + r]);
    float l = 0.f;
    #pragma unroll
    for (int ti = 0; ti < NCT; ti++)
        l += pl[(size_t)ti * SEQ + r] * __expf(pm[(size_t)ti * SEQ + r] - m);
    float il = 1.f / l;
    #pragma unroll
    for (int ti = 0; ti < NCT; ti++)
        pl[(size_t)ti * SEQ + r] = __expf(pm[(size_t)ti * SEQ + r] - m) * il;
}

// ---------------- fixup: out *= factor[tile][row]
__global__ __launch_bounds__(256)
void fixup_kernel(const float* __restrict__ F, const void* __restrict__ X,
                  void* __restrict__ out)
{
    const int isbf = detect_bf16(X);
    size_t g = ((size_t)blockIdx.x * 256 + threadIdx.x) * 8;
    const int row = (int)(g >> 12);
    const int col = (int)(g & (SEQ - 1));
    const float f = F[(size_t)(col >> 7) * SEQ + row];
    if (isbf) {
        unsigned short* p = (unsigned short*)out + g;
        U4 v; v.u = *(const uint4*)p;
        #pragma unroll
        for (int q = 0; q < 8; q++) v.s[q] = f2bf(bf2f(v.s[q]) * f);
        *(uint4*)p = v.u;
    } else {
        float* p = (float*)out + g;
        float4 a = *(const float4*)p;
        float4 b = *(const float4*)(p + 4);
        a.x *= f; a.y *= f; a.z *= f; a.w *= f;
        b.x *= f; b.y *= f; b.z *= f; b.w *= f;
        *(float4*)p = a;
        *(float4*)(p + 4) = b;
    }
}

extern "C" void kernel_launch(void* const* d_in, const int* in_sizes, int n_in,
                              void* d_out, int out_size, void* d_ws, size_t ws_size,
                              hipStream_t stream)
{
    const void* x  = d_in[0];
    const void* wq = d_in[1];
    const void* wk = d_in[2];
    // d_in[3] (w_v), d_in[4] (out_proj) unused by the reference output.

    // Workspace timeline (32 MiB budget):
    //   [0,16M):  w2 partials -> (dead) -> qw partial0 fp32 -> (dead) -> pm/pl at [0,1M)
    //   [16,20M): W2 fp32 (dead after qw_part)
    //   [16,24M): QWhi bf16 (written by qw_reduce_split, after W2 dead)
    //   [24,32M): QWlo bf16
    //   d_out:    qw partial1 fp32 scratch (dead before scores writes P)
    float* ws  = (float*)d_ws;
    float* W2p = ws;
    float* W2  = ws + (size_t)SEQ * DM;
    float* QW0 = ws;
    float* QW1 = (float*)d_out;
    unsigned short* QWhi = (unsigned short*)(ws + (size_t)SEQ * DM);
    unsigned short* QWlo = QWhi + (size_t)SEQ * DM;
    float* pm  = ws;
    float* pl  = pm + (size_t)NCT * SEQ;

    dim3 blk(256);
    // W2 = (1/sqrt(1024)) * wq @ wk^T, split-K=4
    w2_part_kernel<<<dim3(DM / BN, DM / BM, 4), blk, 0, stream>>>(wq, wk, W2p, 0.03125f);
    w2_reduce_kernel<<<dim3(DM * DM / (4 * 256)), blk, 0, stream>>>(W2p, W2);
    // QW = x @ W2, split-K=2
    qw_part_kernel<<<dim3(DM / BN, SEQ / BM, 2), blk, 0, stream>>>(x, W2, QW0, QW1);
    // QW -> bf16 hi/lo split
    qw_reduce_split_kernel<<<dim3(SEQ * DM / (8 * 256)), blk, 0, stream>>>(QW0, QW1, QWhi, QWlo);
    // scores via MFMA + fused softmax partials, P to d_out
    scores_mfma_kernel<<<dim3(SEQ / BN, SEQ / BM), blk, 0, stream>>>(QWhi, QWlo, x, pm, pl, d_out);
    // per-row global max/sum -> per-(tile,row) factors (into pl)
    reduce_kernel<<<dim3(SEQ / 256), blk, 0, stream>>>(pm, pl);
    // out *= factor
    fixup_kernel<<<dim3(SEQ * SEQ / (8 * 256)), blk, 0, stream>>>(pl, x, d_out);
}

// Round 3
// 329.080 us; speedup vs baseline: 3.7492x; 1.1984x over previous
//
#include <hip/hip_runtime.h>
#include <math.h>

#define SEQ 4096
#define DM  1024

#define BM 128
#define BN 128
#define BK 16
#define PAD 4
#define NCT (SEQ / BN)   // 32 column tiles
#define KS 32            // K per MFMA step

typedef __attribute__((ext_vector_type(8))) short bf16x8;
typedef __attribute__((ext_vector_type(4))) float f32x4;

union U4 { uint4 u; unsigned short s[8]; };

__device__ __forceinline__ float bf2f(unsigned short u) {
    return __uint_as_float(((unsigned int)u) << 16);
}
__device__ __forceinline__ unsigned short f2bf(float f) {
    unsigned int u = __float_as_uint(f);
    return (unsigned short)((u + 0x7FFFu + ((u >> 16) & 1u)) >> 16);
}

// Decide whether buffer holds packed bf16 (1) or fp32 (0).
__device__ __forceinline__ int detect_bf16(const void* p0) {
    const unsigned int* p = (const unsigned int*)p0;
    int cnt = 0;
    #pragma unroll
    for (int i = 0; i < 64; i++) {
        unsigned int e = (p[i] >> 7) & 0xFFu;
        cnt += (e >= 112u && e <= 140u) ? 1 : 0;
    }
    return cnt >= 48 ? 1 : 0;
}

// load 8 consecutive elements (element index idx, multiple of 8) as fp32
__device__ __forceinline__ void load8(const void* base, size_t idx, int isbf, float* v) {
    if (isbf) {
        U4 t; t.u = *(const uint4*)((const unsigned short*)base + idx);
        #pragma unroll
        for (int q = 0; q < 8; q++) v[q] = bf2f(t.s[q]);
    } else {
        const float* f = (const float*)base + idx;
        float4 a = *(const float4*)f;
        float4 b = *(const float4*)(f + 4);
        v[0] = a.x; v[1] = a.y; v[2] = a.z; v[3] = a.w;
        v[4] = b.x; v[5] = b.y; v[6] = b.z; v[7] = b.w;
    }
}

// async global -> LDS, 16 bytes per lane (linear LDS dest: base + lane*16)
__device__ __forceinline__ void gl16(const void* g, void* l) {
    __builtin_amdgcn_global_load_lds(
        (const __attribute__((address_space(1))) unsigned int*)g,
        (__attribute__((address_space(3))) unsigned int*)l, 16, 0, 0);
}

// ---------------- xsplit: X (fp32 or bf16) -> exact bf16 hi/lo pair
__global__ __launch_bounds__(256)
void xsplit_kernel(const void* __restrict__ X, unsigned short* __restrict__ Hi,
                   unsigned short* __restrict__ Lo)
{
    const int isbf = detect_bf16(X);
    size_t i = ((size_t)blockIdx.x * 256 + threadIdx.x) * 8;
    float v[8];
    load8(X, i, isbf, v);
    U4 h, l;
    #pragma unroll
    for (int q = 0; q < 8; q++) {
        h.s[q] = f2bf(v[q]);
        l.s[q] = f2bf(v[q] - bf2f(h.s[q]));
    }
    *(uint4*)(Hi + i) = h.u;
    *(uint4*)(Lo + i) = l.u;
}

// ---------------- W2T partial: P[kz][n,d] = scale * sum_{e in chunk kz} wk[n,e]*wq[d,e]
// (called with A=wk, B=wq so the output is W2^T, K-contiguous for the qw NT GEMM)
__global__ __launch_bounds__(256)
void w2_part_kernel(const void* __restrict__ Wa, const void* __restrict__ Wb,
                    float* __restrict__ P, float scale)
{
    __shared__ float As[BK][BM + PAD];
    __shared__ float Bs[BK][BN + PAD];
    const int isa = detect_bf16(Wa);
    const int isb = detect_bf16(Wb);
    const int t  = threadIdx.x;
    const int bx = blockIdx.x;
    const int by = blockIdx.y;
    const int kz = blockIdx.z;
    const int tm = t >> 4, tn = t & 15;

    float acc[8][8];
    #pragma unroll
    for (int i = 0; i < 8; i++)
        #pragma unroll
        for (int j = 0; j < 8; j++) acc[i][j] = 0.f;

    const int ar = t >> 1;
    const int ak = (t & 1) * 8;
    const int k0 = kz * (DM / 4);

    for (int kt = k0; kt < k0 + DM / 4; kt += BK) {
        float av[8], bv[8];
        load8(Wa, (size_t)(by * BM + ar) * DM + kt + ak, isa, av);
        load8(Wb, (size_t)(bx * BN + ar) * DM + kt + ak, isb, bv);
        #pragma unroll
        for (int q = 0; q < 8; q++) As[ak + q][ar] = av[q];
        #pragma unroll
        for (int q = 0; q < 8; q++) Bs[ak + q][ar] = bv[q];
        __syncthreads();
        #pragma unroll
        for (int kk = 0; kk < BK; kk++) {
            float a[8], b[8];
            #pragma unroll
            for (int i = 0; i < 8; i++) a[i] = As[kk][tm * 8 + i];
            #pragma unroll
            for (int j = 0; j < 8; j++) b[j] = Bs[kk][tn * 8 + j];
            #pragma unroll
            for (int i = 0; i < 8; i++)
                #pragma unroll
                for (int j = 0; j < 8; j++)
                    acc[i][j] = fmaf(a[i], b[j], acc[i][j]);
        }
        __syncthreads();
    }
    float* base = P + (size_t)kz * DM * DM;
    #pragma unroll
    for (int i = 0; i < 8; i++) {
        float* cp = base + (size_t)(by * BM + tm * 8 + i) * DM + bx * BN + tn * 8;
        #pragma unroll
        for (int j = 0; j < 8; j++) cp[j] = acc[i][j] * scale;
    }
}

// ---------------- W2T = sum of 4 K-chunk partials -> bf16 hi/lo split
__global__ __launch_bounds__(256)
void w2_reduce_split_kernel(const float* __restrict__ P, unsigned short* __restrict__ Hi,
                            unsigned short* __restrict__ Lo)
{
    const size_t N = (size_t)DM * DM;
    size_t i = ((size_t)blockIdx.x * 256 + threadIdx.x) * 8;
    float v[8];
    #pragma unroll
    for (int h = 0; h < 8; h += 4) {
        float4 a = *(const float4*)(P + i + h);
        float4 b = *(const float4*)(P + N + i + h);
        float4 c = *(const float4*)(P + 2 * N + i + h);
        float4 d = *(const float4*)(P + 3 * N + i + h);
        v[h + 0] = a.x + b.x + c.x + d.x;
        v[h + 1] = a.y + b.y + c.y + d.y;
        v[h + 2] = a.z + b.z + c.z + d.z;
        v[h + 3] = a.w + b.w + c.w + d.w;
    }
    U4 h, l;
    #pragma unroll
    for (int q = 0; q < 8; q++) {
        h.s[q] = f2bf(v[q]);
        l.s[q] = f2bf(v[q] - bf2f(h.s[q]));
    }
    *(uint4*)(Hi + i) = h.u;
    *(uint4*)(Lo + i) = l.u;
}

// ---------------- QW = Xs @ W2T^T via MFMA, 4-term split (fp32-grade accuracy)
// NT GEMM identical in structure to scores_mfma: 128x128 tile, 4 waves, KS=32,
// XOR-swizzled-source gl16 staging. split-K=2: kz=0 -> O0 (ws), kz=1 -> O1 (d_out).
__global__ __launch_bounds__(256)
void qw_mfma_kernel(const unsigned short* __restrict__ Ahi, const unsigned short* __restrict__ Alo,
                    const unsigned short* __restrict__ Bhi, const unsigned short* __restrict__ Blo,
                    float* __restrict__ O0, float* __restrict__ O1)
{
    __shared__ unsigned short lAhi[128 * KS];
    __shared__ unsigned short lAlo[128 * KS];
    __shared__ unsigned short lBhi[128 * KS];
    __shared__ unsigned short lBlo[128 * KS];

    const int t    = threadIdx.x;
    const int bx   = blockIdx.x;   // n tile over DM (8)
    const int by   = blockIdx.y;   // m tile over SEQ (32)
    const int kz   = blockIdx.z;   // k chunk (0/1)
    const int lane = t & 63;
    const int w    = t >> 6;
    const int wr   = w >> 1;
    const int wc   = w & 1;
    const int fr   = lane & 15;
    const int fq   = lane >> 4;

    f32x4 acc[4][4];
    #pragma unroll
    for (int i = 0; i < 4; i++)
        #pragma unroll
        for (int j = 0; j < 4; j++)
            acc[i][j] = (f32x4){0.f, 0.f, 0.f, 0.f};

    const int trow = t >> 2;
    const int tcs  = t & 3;
    const int k0   = kz * (DM / 2);

    for (int kt = k0; kt < k0 + DM / 2; kt += KS) {
        #pragma unroll
        for (int p = 0; p < 2; p++) {
            const int row = p * 64 + trow;
            const int sc  = tcs ^ ((row >> 1) & 3);
            const int lof = (p * 256 + t) * 16;
            const size_t ga = (size_t)(by * BM + row) * DM + kt + sc * 8;
            const size_t gb = (size_t)(bx * BN + row) * DM + kt + sc * 8;
            gl16(Ahi + ga, (char*)lAhi + lof);
            gl16(Alo + ga, (char*)lAlo + lof);
            gl16(Bhi + gb, (char*)lBhi + lof);
            gl16(Blo + gb, (char*)lBlo + lof);
        }
        __syncthreads();

        bf16x8 bh[4], bl[4];
        #pragma unroll
        for (int nj = 0; nj < 4; nj++) {
            const int br = wc * 64 + nj * 16 + fr;
            const int bc = fq ^ ((br >> 1) & 3);
            bh[nj] = *(const bf16x8*)&lBhi[br * KS + bc * 8];
            bl[nj] = *(const bf16x8*)&lBlo[br * KS + bc * 8];
        }
        #pragma unroll
        for (int mi = 0; mi < 4; mi++) {
            const int ar_ = wr * 64 + mi * 16 + fr;
            const int ac_ = fq ^ ((ar_ >> 1) & 3);
            bf16x8 ah = *(const bf16x8*)&lAhi[ar_ * KS + ac_ * 8];
            bf16x8 al = *(const bf16x8*)&lAlo[ar_ * KS + ac_ * 8];
            #pragma unroll
            for (int nj = 0; nj < 4; nj++) {
                acc[mi][nj] = __builtin_amdgcn_mfma_f32_16x16x32_bf16(ah, bh[nj], acc[mi][nj], 0, 0, 0);
                acc[mi][nj] = __builtin_amdgcn_mfma_f32_16x16x32_bf16(al, bh[nj], acc[mi][nj], 0, 0, 0);
                acc[mi][nj] = __builtin_amdgcn_mfma_f32_16x16x32_bf16(ah, bl[nj], acc[mi][nj], 0, 0, 0);
                acc[mi][nj] = __builtin_amdgcn_mfma_f32_16x16x32_bf16(al, bl[nj], acc[mi][nj], 0, 0, 0);
            }
        }
        __syncthreads();
    }

    float* O = kz ? O1 : O0;
    #pragma unroll
    for (int mi = 0; mi < 4; mi++)
        #pragma unroll
        for (int reg = 0; reg < 4; reg++) {
            const int row = by * BM + wr * 64 + mi * 16 + fq * 4 + reg;
            #pragma unroll
            for (int nj = 0; nj < 4; nj++) {
                const int col = bx * BN + wc * 64 + nj * 16 + fr;
                O[(size_t)row * DM + col] = acc[mi][nj][reg];
            }
        }
}

// ---------------- QW = P0 + P1, split into bf16 hi/lo pair (for scores A operand)
__global__ __launch_bounds__(256)
void qw_combine_split_kernel(const float* __restrict__ P0, const float* __restrict__ P1,
                             unsigned short* __restrict__ Hi, unsigned short* __restrict__ Lo)
{
    size_t i = ((size_t)blockIdx.x * 256 + threadIdx.x) * 8;
    float4 a0 = *(const float4*)(P0 + i);
    float4 a1 = *(const float4*)(P0 + i + 4);
    float4 b0 = *(const float4*)(P1 + i);
    float4 b1 = *(const float4*)(P1 + i + 4);
    float v[8] = {a0.x + b0.x, a0.y + b0.y, a0.z + b0.z, a0.w + b0.w,
                  a1.x + b1.x, a1.y + b1.y, a1.z + b1.z, a1.w + b1.w};
    U4 h, l;
    #pragma unroll
    for (int q = 0; q < 8; q++) {
        h.s[q] = f2bf(v[q]);
        l.s[q] = f2bf(v[q] - bf2f(h.s[q]));
    }
    *(uint4*)(Hi + i) = h.u;
    *(uint4*)(Lo + i) = l.u;
}

// ---------------- scores via MFMA: S = (QWhi+QWlo) @ X^T, fused softmax partials.
__global__ __launch_bounds__(256)
void scores_mfma_kernel(const unsigned short* __restrict__ QWhi,
                        const unsigned short* __restrict__ QWlo,
                        const void* __restrict__ X,
                        float* __restrict__ pm, float* __restrict__ pl,
                        void* __restrict__ out)
{
    __shared__ unsigned short lAhi[128 * KS];
    __shared__ unsigned short lAlo[128 * KS];
    __shared__ unsigned short lBhi[128 * KS];
    __shared__ unsigned short lBlo[128 * KS];
    __shared__ float smax[128][2];
    __shared__ float ssum[128][2];

    const int isbf = detect_bf16(X);
    const int t    = threadIdx.x;
    const int bx   = blockIdx.x;   // col tile
    const int by   = blockIdx.y;   // row tile
    const int lane = t & 63;
    const int w    = t >> 6;
    const int wr   = w >> 1;
    const int wc   = w & 1;
    const int fr   = lane & 15;
    const int fq   = lane >> 4;

    f32x4 acc[4][4];
    #pragma unroll
    for (int i = 0; i < 4; i++)
        #pragma unroll
        for (int j = 0; j < 4; j++)
            acc[i][j] = (f32x4){0.f, 0.f, 0.f, 0.f};

    const int trow = t >> 2;
    const int tcs  = t & 3;

    for (int kt = 0; kt < DM; kt += KS) {
        #pragma unroll
        for (int p = 0; p < 2; p++) {
            const int row = p * 64 + trow;
            const int sc  = tcs ^ ((row >> 1) & 3);
            const int lof = (p * 256 + t) * 16;
            const size_t ga = (size_t)(by * BM + row) * DM + kt + sc * 8;
            gl16(QWhi + ga, (char*)lAhi + lof);
            gl16(QWlo + ga, (char*)lAlo + lof);
            if (isbf) {
                const size_t gb = (size_t)(bx * BN + row) * DM + kt + sc * 8;
                gl16((const unsigned short*)X + gb, (char*)lBhi + lof);
            }
        }
        if (!isbf) {
            const int row  = t >> 1;
            const int half = t & 1;
            const float* xp = (const float*)X + (size_t)(bx * BN + row) * DM + kt + half * 16;
            float4 v0 = ((const float4*)xp)[0];
            float4 v1 = ((const float4*)xp)[1];
            float4 v2 = ((const float4*)xp)[2];
            float4 v3 = ((const float4*)xp)[3];
            float vv[16] = {v0.x, v0.y, v0.z, v0.w, v1.x, v1.y, v1.z, v1.w,
                            v2.x, v2.y, v2.z, v2.w, v3.x, v3.y, v3.z, v3.w};
            U4 h0, h1, l0, l1;
            #pragma unroll
            for (int q = 0; q < 8; q++) {
                h0.s[q] = f2bf(vv[q]);
                l0.s[q] = f2bf(vv[q] - bf2f(h0.s[q]));
                h1.s[q] = f2bf(vv[8 + q]);
                l1.s[q] = f2bf(vv[8 + q] - bf2f(h1.s[q]));
            }
            const int s  = (row >> 1) & 3;
            const int ca = (2 * half) ^ s;
            const int cb = (2 * half + 1) ^ s;
            *(uint4*)&lBhi[row * KS + ca * 8] = h0.u;
            *(uint4*)&lBhi[row * KS + cb * 8] = h1.u;
            *(uint4*)&lBlo[row * KS + ca * 8] = l0.u;
            *(uint4*)&lBlo[row * KS + cb * 8] = l1.u;
        }
        __syncthreads();

        bf16x8 bh[4];
        #pragma unroll
        for (int nj = 0; nj < 4; nj++) {
            const int br = wc * 64 + nj * 16 + fr;
            const int bc = fq ^ ((br >> 1) & 3);
            bh[nj] = *(const bf16x8*)&lBhi[br * KS + bc * 8];
        }
        #pragma unroll
        for (int mi = 0; mi < 4; mi++) {
            const int ar_ = wr * 64 + mi * 16 + fr;
            const int ac_ = fq ^ ((ar_ >> 1) & 3);
            bf16x8 ah = *(const bf16x8*)&lAhi[ar_ * KS + ac_ * 8];
            bf16x8 al = *(const bf16x8*)&lAlo[ar_ * KS + ac_ * 8];
            #pragma unroll
            for (int nj = 0; nj < 4; nj++) {
                acc[mi][nj] = __builtin_amdgcn_mfma_f32_16x16x32_bf16(ah, bh[nj], acc[mi][nj], 0, 0, 0);
                acc[mi][nj] = __builtin_amdgcn_mfma_f32_16x16x32_bf16(al, bh[nj], acc[mi][nj], 0, 0, 0);
            }
        }
        if (!isbf) {
            bf16x8 bl[4];
            #pragma unroll
            for (int nj = 0; nj < 4; nj++) {
                const int br = wc * 64 + nj * 16 + fr;
                const int bc = fq ^ ((br >> 1) & 3);
                bl[nj] = *(const bf16x8*)&lBlo[br * KS + bc * 8];
            }
            #pragma unroll
            for (int mi = 0; mi < 4; mi++) {
                const int ar_ = wr * 64 + mi * 16 + fr;
                const int ac_ = fq ^ ((ar_ >> 1) & 3);
                bf16x8 ah = *(const bf16x8*)&lAhi[ar_ * KS + ac_ * 8];
                #pragma unroll
                for (int nj = 0; nj < 4; nj++)
                    acc[mi][nj] = __builtin_amdgcn_mfma_f32_16x16x32_bf16(ah, bl[nj], acc[mi][nj], 0, 0, 0);
            }
        }
        __syncthreads();
    }

    // ---- fused softmax epilogue ----
    float rmx[4][4];
    #pragma unroll
    for (int mi = 0; mi < 4; mi++)
        #pragma unroll
        for (int reg = 0; reg < 4; reg++) {
            float m = acc[mi][0][reg];
            #pragma unroll
            for (int nj = 1; nj < 4; nj++) m = fmaxf(m, acc[mi][nj][reg]);
            m = fmaxf(m, __shfl_xor(m, 1, 64));
            m = fmaxf(m, __shfl_xor(m, 2, 64));
            m = fmaxf(m, __shfl_xor(m, 4, 64));
            m = fmaxf(m, __shfl_xor(m, 8, 64));
            rmx[mi][reg] = m;
        }
    if (fr == 0) {
        #pragma unroll
        for (int mi = 0; mi < 4; mi++)
            #pragma unroll
            for (int reg = 0; reg < 4; reg++)
                smax[wr * 64 + mi * 16 + fq * 4 + reg][wc] = rmx[mi][reg];
    }
    __syncthreads();
    float mt[4][4];
    #pragma unroll
    for (int mi = 0; mi < 4; mi++)
        #pragma unroll
        for (int reg = 0; reg < 4; reg++) {
            const int r = wr * 64 + mi * 16 + fq * 4 + reg;
            mt[mi][reg] = fmaxf(smax[r][0], smax[r][1]);
        }
    float rsm[4][4];
    #pragma unroll
    for (int mi = 0; mi < 4; mi++)
        #pragma unroll
        for (int reg = 0; reg < 4; reg++) rsm[mi][reg] = 0.f;
    #pragma unroll
    for (int mi = 0; mi < 4; mi++)
        #pragma unroll
        for (int nj = 0; nj < 4; nj++)
            #pragma unroll
            for (int reg = 0; reg < 4; reg++) {
                float e = __expf(acc[mi][nj][reg] - mt[mi][reg]);
                acc[mi][nj][reg] = e;
                rsm[mi][reg] += e;
            }
    #pragma unroll
    for (int mi = 0; mi < 4; mi++)
        #pragma unroll
        for (int reg = 0; reg < 4; reg++) {
            float s = rsm[mi][reg];
            s += __shfl_xor(s, 1, 64);
            s += __shfl_xor(s, 2, 64);
            s += __shfl_xor(s, 4, 64);
            s += __shfl_xor(s, 8, 64);
            if (fr == 0) ssum[wr * 64 + mi * 16 + fq * 4 + reg][wc] = s;
        }
    #pragma unroll
    for (int mi = 0; mi < 4; mi++)
        #pragma unroll
        for (int reg = 0; reg < 4; reg++) {
            const int row = by * BM + wr * 64 + mi * 16 + fq * 4 + reg;
            #pragma unroll
            for (int nj = 0; nj < 4; nj++) {
                const int col = bx * BN + wc * 64 + nj * 16 + fr;
                const float v = acc[mi][nj][reg];
                if (isbf)
                    ((unsigned short*)out)[(size_t)row * SEQ + col] = f2bf(v);
                else
                    ((float*)out)[(size_t)row * SEQ + col] = v;
            }
        }
    __syncthreads();
    if (t < 128) {
        const int grow = by * BM + t;
        pm[(size_t)bx * SEQ + grow] = fmaxf(smax[t][0], smax[t][1]);
        pl[(size_t)bx * SEQ + grow] = ssum[t][0] + ssum[t][1];
    }
}

// ---------------- global reduce: m,l per row -> per-(tile,row) factor exp(m_t - m)/l
__global__ __launch_bounds__(256)
void reduce_kernel(const float* __restrict__ pm, float* __restrict__ pl)
{
    int r = blockIdx.x * 256 + threadIdx.x;
    if (r >= SEQ) return;
    float m = pm[r];
    #pragma unroll
    for (int ti = 1; ti < NCT; ti++) m = fmaxf(m, pm[(size_t)ti * SEQ + r]);
    float l = 0.f;
    #pragma unroll
    for (int ti = 0; ti < NCT; ti++)
        l += pl[(size_t)ti * SEQ + r] * __expf(pm[(size_t)ti * SEQ + r] - m);
    float il = 1.f / l;
    #pragma unroll
    for (int ti = 0; ti < NCT; ti++)
        pl[(size_t)ti * SEQ + r] = __expf(pm[(size_t)ti * SEQ + r] - m) * il;
}

// ---------------- fixup: out *= factor[tile][row]
__global__ __launch_bounds__(256)
void fixup_kernel(const float* __restrict__ F, const void* __restrict__ X,
                  void* __restrict__ out)
{
    const int isbf = detect_bf16(X);
    size_t g = ((size_t)blockIdx.x * 256 + threadIdx.x) * 8;
    const int row = (int)(g >> 12);
    const int col = (int)(g & (SEQ - 1));
    const float f = F[(size_t)(col >> 7) * SEQ + row];
    if (isbf) {
        unsigned short* p = (unsigned short*)out + g;
        U4 v; v.u = *(const uint4*)p;
        #pragma unroll
        for (int q = 0; q < 8; q++) v.s[q] = f2bf(bf2f(v.s[q]) * f);
        *(uint4*)p = v.u;
    } else {
        float* p = (float*)out + g;
        float4 a = *(const float4*)p;
        float4 b = *(const float4*)(p + 4);
        a.x *= f; a.y *= f; a.z *= f; a.w *= f;
        b.x *= f; b.y *= f; b.z *= f; b.w *= f;
        *(float4*)p = a;
        *(float4*)(p + 4) = b;
    }
}

extern "C" void kernel_launch(void* const* d_in, const int* in_sizes, int n_in,
                              void* d_out, int out_size, void* d_ws, size_t ws_size,
                              hipStream_t stream)
{
    const void* x  = d_in[0];
    const void* wq = d_in[1];
    const void* wk = d_in[2];
    // d_in[3] (w_v), d_in[4] (out_proj) unused by the reference output.

    // Buffer timeline (ws <= 32 MiB, d_out = 64 MiB scratch until scores):
    //   phase            ws[0,8M)  ws[8,16M)  ws[16,32M)        d_out
    //   1 xsplit         Xhi<-     Xlo<-      -                 -
    //   2 w2_part        (Xhi)     (Xlo)      W2T partials<-    -
    //   3 w2_red_split   (Xhi)     (Xlo)      ->read            W2Thi/lo<- [0,4M)
    //   4 qw_mfma        ->read    ->read     QP0<- (16M)       ->W2T read; QP1<- [16,32M)
    //   5 qw_combine     QWhi<-    QWlo<-     ->QP0 read        ->QP1 read
    //   6 scores         ->read    ->read     pm/pl<- [16,17M)  P<- [0,64M)
    //   7 reduce/fixup   -         -          pm/pl r/w         P r/w
    // All same-phase read/write regions are disjoint; cross-phase ordering is
    // stream-sequential.
    char* wsb = (char*)d_ws;
    char* dob = (char*)d_out;
    unsigned short* Xhi  = (unsigned short*)wsb;
    unsigned short* Xlo  = (unsigned short*)(wsb + ((size_t)8 << 20));
    float*          W2P  = (float*)(wsb + ((size_t)16 << 20));
    float*          QP0  = W2P;
    unsigned short* QWhi = (unsigned short*)wsb;
    unsigned short* QWlo = (unsigned short*)(wsb + ((size_t)8 << 20));
    float*          pm   = (float*)(wsb + ((size_t)16 << 20));
    float*          pl   = pm + (size_t)NCT * SEQ;
    unsigned short* W2Thi = (unsigned short*)dob;
    unsigned short* W2Tlo = (unsigned short*)(dob + ((size_t)2 << 20));
    float*          QP1   = (float*)(dob + ((size_t)16 << 20));

    dim3 blk(256);
    // 1. X -> bf16 hi/lo split
    xsplit_kernel<<<dim3(SEQ * DM / (8 * 256)), blk, 0, stream>>>(x, Xhi, Xlo);
    // 2. W2T = (1/sqrt(1024)) * wk @ wq^T (note swapped args -> transposed), split-K=4
    w2_part_kernel<<<dim3(DM / BN, DM / BM, 4), blk, 0, stream>>>(wk, wq, W2P, 0.03125f);
    // 3. sum partials -> W2T bf16 hi/lo
    w2_reduce_split_kernel<<<dim3(DM * DM / (8 * 256)), blk, 0, stream>>>(W2P, W2Thi, W2Tlo);
    // 4. QW = Xs @ W2T^T via 4-term split MFMA, split-K=2
    qw_mfma_kernel<<<dim3(DM / BN, SEQ / BM, 2), blk, 0, stream>>>(Xhi, Xlo, W2Thi, W2Tlo, QP0, QP1);
    // 5. QW partial sum -> bf16 hi/lo
    qw_combine_split_kernel<<<dim3(SEQ * DM / (8 * 256)), blk, 0, stream>>>(QP0, QP1, QWhi, QWlo);
    // 6. scores via MFMA + fused softmax partials, P to d_out
    scores_mfma_kernel<<<dim3(SEQ / BN, SEQ / BM), blk, 0, stream>>>(QWhi, QWlo, x, pm, pl, d_out);
    // 7. per-row global max/sum -> per-(tile,row) factors (into pl)
    reduce_kernel<<<dim3(SEQ / 256), blk, 0, stream>>>(pm, pl);
    // 8. out *= factor
    fixup_kernel<<<dim3(SEQ * SEQ / (8 * 256)), blk, 0, stream>>>(pl, x, d_out);
}

// Round 4
// 305.948 us; speedup vs baseline: 4.0327x; 1.0756x over previous
//
#include <hip/hip_runtime.h>
#include <math.h>

#define SEQ 4096
#define DM  1024

#define BM 128
#define BN 128
#define NCT (SEQ / BN)   // 32 column tiles
#define KS 32            // K per MFMA step

typedef __attribute__((ext_vector_type(8))) short bf16x8;
typedef __attribute__((ext_vector_type(4))) float f32x4;

union U4 { uint4 u; unsigned short s[8]; };

__device__ __forceinline__ float bf2f(unsigned short u) {
    return __uint_as_float(((unsigned int)u) << 16);
}
__device__ __forceinline__ unsigned short f2bf(float f) {
    unsigned int u = __float_as_uint(f);
    return (unsigned short)((u + 0x7FFFu + ((u >> 16) & 1u)) >> 16);
}

// Decide whether buffer holds packed bf16 (1) or fp32 (0).
__device__ __forceinline__ int detect_bf16(const void* p0) {
    const unsigned int* p = (const unsigned int*)p0;
    int cnt = 0;
    #pragma unroll
    for (int i = 0; i < 64; i++) {
        unsigned int e = (p[i] >> 7) & 0xFFu;
        cnt += (e >= 112u && e <= 140u) ? 1 : 0;
    }
    return cnt >= 48 ? 1 : 0;
}

// load 8 consecutive elements (element index idx, multiple of 8) as fp32
__device__ __forceinline__ void load8(const void* base, size_t idx, int isbf, float* v) {
    if (isbf) {
        U4 t; t.u = *(const uint4*)((const unsigned short*)base + idx);
        #pragma unroll
        for (int q = 0; q < 8; q++) v[q] = bf2f(t.s[q]);
    } else {
        const float* f = (const float*)base + idx;
        float4 a = *(const float4*)f;
        float4 b = *(const float4*)(f + 4);
        v[0] = a.x; v[1] = a.y; v[2] = a.z; v[3] = a.w;
        v[4] = b.x; v[5] = b.y; v[6] = b.z; v[7] = b.w;
    }
}

// async global -> LDS, 16 bytes per lane (linear LDS dest: base + lane*16)
__device__ __forceinline__ void gl16(const void* g, void* l) {
    __builtin_amdgcn_global_load_lds(
        (const __attribute__((address_space(1))) unsigned int*)g,
        (__attribute__((address_space(3))) unsigned int*)l, 16, 0, 0);
}

// ---------------- split3: x / wq / wk -> exact bf16 hi/lo pairs, one pass.
// blocks [0,2048): x (4M elems); [2048,2560): wq (1M); [2560,3072): wk (1M)
__global__ __launch_bounds__(256)
void split3_kernel(const void* __restrict__ X, const void* __restrict__ Wq,
                   const void* __restrict__ Wk,
                   unsigned short* __restrict__ Xhi, unsigned short* __restrict__ Xlo,
                   unsigned short* __restrict__ Wqhi, unsigned short* __restrict__ Wqlo,
                   unsigned short* __restrict__ Wkhi, unsigned short* __restrict__ Wklo)
{
    const int b = blockIdx.x;
    const void* src;
    unsigned short *Hi, *Lo;
    size_t i;
    if (b < 2048)      { src = X;  Hi = Xhi;  Lo = Xlo;  i = ((size_t)b * 256 + threadIdx.x) * 8; }
    else if (b < 2560) { src = Wq; Hi = Wqhi; Lo = Wqlo; i = ((size_t)(b - 2048) * 256 + threadIdx.x) * 8; }
    else               { src = Wk; Hi = Wkhi; Lo = Wklo; i = ((size_t)(b - 2560) * 256 + threadIdx.x) * 8; }
    const int isbf = detect_bf16(src);
    float v[8];
    load8(src, i, isbf, v);
    U4 h, l;
    #pragma unroll
    for (int q = 0; q < 8; q++) {
        h.s[q] = f2bf(v[q]);
        l.s[q] = f2bf(v[q] - bf2f(h.s[q]));
    }
    *(uint4*)(Hi + i) = h.u;
    *(uint4*)(Lo + i) = l.u;
}

// ---------------- generic NT split-bf16 MFMA partial GEMM:
// O[kz*pstride + m*DM + n] = scale * sum_{k in chunk kz} A[m,k]*B[n,k]
// A = Ahi+Alo, B = Bhi+Blo (exact splits), 4 cross terms -> fp32-grade accuracy.
// 128x128 tile, 4 waves, KS=32, XOR-swizzled-source gl16 staging (linear LDS dest).
// Grid (8, M/128, KZ) with bijective XCD swizzle (nwg % 8 == 0 in both uses).
__global__ __launch_bounds__(256)
void part_mfma_kernel(const unsigned short* __restrict__ Ahi, const unsigned short* __restrict__ Alo,
                      const unsigned short* __restrict__ Bhi, const unsigned short* __restrict__ Blo,
                      float* __restrict__ O, int kchunk, size_t pstride, float scale)
{
    __shared__ unsigned short lAhi[128 * KS];
    __shared__ unsigned short lAlo[128 * KS];
    __shared__ unsigned short lBhi[128 * KS];
    __shared__ unsigned short lBlo[128 * KS];

    const int t = threadIdx.x;
    // XCD-aware bijective remap (T1): consecutive-on-XCD blocks sweep bx fastest
    // -> B panel (<=4MB) L2-hot, A chunk reused across the sweep.
    const int gy  = gridDim.y;
    const int nwg = 8 * gy * gridDim.z;
    const int lid = (blockIdx.z * gy + blockIdx.y) * 8 + blockIdx.x;
    const int swz = (lid & 7) * (nwg >> 3) + (lid >> 3);
    const int bx  = swz & 7;
    const int rst = swz >> 3;
    const int by  = rst % gy;
    const int kz  = rst / gy;

    const int lane = t & 63;
    const int w    = t >> 6;
    const int wr   = w >> 1;
    const int wc   = w & 1;
    const int fr   = lane & 15;
    const int fq   = lane >> 4;

    f32x4 acc[4][4];
    #pragma unroll
    for (int i = 0; i < 4; i++)
        #pragma unroll
        for (int j = 0; j < 4; j++)
            acc[i][j] = (f32x4){0.f, 0.f, 0.f, 0.f};

    const int trow = t >> 2;
    const int tcs  = t & 3;
    const int k0   = kz * kchunk;

    for (int kt = k0; kt < k0 + kchunk; kt += KS) {
        #pragma unroll
        for (int p = 0; p < 2; p++) {
            const int row = p * 64 + trow;
            const int sc  = tcs ^ ((row >> 1) & 3);
            const int lof = (p * 256 + t) * 16;
            const size_t ga = (size_t)(by * BM + row) * DM + kt + sc * 8;
            const size_t gb = (size_t)(bx * BN + row) * DM + kt + sc * 8;
            gl16(Ahi + ga, (char*)lAhi + lof);
            gl16(Alo + ga, (char*)lAlo + lof);
            gl16(Bhi + gb, (char*)lBhi + lof);
            gl16(Blo + gb, (char*)lBlo + lof);
        }
        __syncthreads();

        bf16x8 bh[4], bl[4];
        #pragma unroll
        for (int nj = 0; nj < 4; nj++) {
            const int br = wc * 64 + nj * 16 + fr;
            const int bc = fq ^ ((br >> 1) & 3);
            bh[nj] = *(const bf16x8*)&lBhi[br * KS + bc * 8];
            bl[nj] = *(const bf16x8*)&lBlo[br * KS + bc * 8];
        }
        #pragma unroll
        for (int mi = 0; mi < 4; mi++) {
            const int ar_ = wr * 64 + mi * 16 + fr;
            const int ac_ = fq ^ ((ar_ >> 1) & 3);
            bf16x8 ah = *(const bf16x8*)&lAhi[ar_ * KS + ac_ * 8];
            bf16x8 al = *(const bf16x8*)&lAlo[ar_ * KS + ac_ * 8];
            #pragma unroll
            for (int nj = 0; nj < 4; nj++) {
                acc[mi][nj] = __builtin_amdgcn_mfma_f32_16x16x32_bf16(ah, bh[nj], acc[mi][nj], 0, 0, 0);
                acc[mi][nj] = __builtin_amdgcn_mfma_f32_16x16x32_bf16(al, bh[nj], acc[mi][nj], 0, 0, 0);
                acc[mi][nj] = __builtin_amdgcn_mfma_f32_16x16x32_bf16(ah, bl[nj], acc[mi][nj], 0, 0, 0);
                acc[mi][nj] = __builtin_amdgcn_mfma_f32_16x16x32_bf16(al, bl[nj], acc[mi][nj], 0, 0, 0);
            }
        }
        __syncthreads();
    }

    float* Op = O + (size_t)kz * pstride;
    #pragma unroll
    for (int mi = 0; mi < 4; mi++)
        #pragma unroll
        for (int reg = 0; reg < 4; reg++) {
            const int row = by * BM + wr * 64 + mi * 16 + fq * 4 + reg;
            #pragma unroll
            for (int nj = 0; nj < 4; nj++) {
                const int col = bx * BN + wc * 64 + nj * 16 + fr;
                Op[(size_t)row * DM + col] = acc[mi][nj][reg] * scale;
            }
        }
}

// ---------------- W2T = sum of 4 K-chunk partials -> bf16 hi/lo split
__global__ __launch_bounds__(256)
void w2_reduce_split_kernel(const float* __restrict__ P, unsigned short* __restrict__ Hi,
                            unsigned short* __restrict__ Lo)
{
    const size_t N = (size_t)DM * DM;
    size_t i = ((size_t)blockIdx.x * 256 + threadIdx.x) * 8;
    float v[8];
    #pragma unroll
    for (int h = 0; h < 8; h += 4) {
        float4 a = *(const float4*)(P + i + h);
        float4 b = *(const float4*)(P + N + i + h);
        float4 c = *(const float4*)(P + 2 * N + i + h);
        float4 d = *(const float4*)(P + 3 * N + i + h);
        v[h + 0] = a.x + b.x + c.x + d.x;
        v[h + 1] = a.y + b.y + c.y + d.y;
        v[h + 2] = a.z + b.z + c.z + d.z;
        v[h + 3] = a.w + b.w + c.w + d.w;
    }
    U4 h, l;
    #pragma unroll
    for (int q = 0; q < 8; q++) {
        h.s[q] = f2bf(v[q]);
        l.s[q] = f2bf(v[q] - bf2f(h.s[q]));
    }
    *(uint4*)(Hi + i) = h.u;
    *(uint4*)(Lo + i) = l.u;
}

// ---------------- QW = P0 + P1, split into bf16 hi/lo pair (for scores A operand)
__global__ __launch_bounds__(256)
void qw_combine_split_kernel(const float* __restrict__ P0, const float* __restrict__ P1,
                             unsigned short* __restrict__ Hi, unsigned short* __restrict__ Lo)
{
    size_t i = ((size_t)blockIdx.x * 256 + threadIdx.x) * 8;
    float4 a0 = *(const float4*)(P0 + i);
    float4 a1 = *(const float4*)(P0 + i + 4);
    float4 b0 = *(const float4*)(P1 + i);
    float4 b1 = *(const float4*)(P1 + i + 4);
    float v[8] = {a0.x + b0.x, a0.y + b0.y, a0.z + b0.z, a0.w + b0.w,
                  a1.x + b1.x, a1.y + b1.y, a1.z + b1.z, a1.w + b1.w};
    U4 h, l;
    #pragma unroll
    for (int q = 0; q < 8; q++) {
        h.s[q] = f2bf(v[q]);
        l.s[q] = f2bf(v[q] - bf2f(h.s[q]));
    }
    *(uint4*)(Hi + i) = h.u;
    *(uint4*)(Lo + i) = l.u;
}

// ---------------- scores via MFMA: S = (QWhi+QWlo) @ X^T, fused softmax partials.
__global__ __launch_bounds__(256)
void scores_mfma_kernel(const unsigned short* __restrict__ QWhi,
                        const unsigned short* __restrict__ QWlo,
                        const void* __restrict__ X,
                        float* __restrict__ pm, float* __restrict__ pl,
                        void* __restrict__ out)
{
    __shared__ unsigned short lAhi[128 * KS];
    __shared__ unsigned short lAlo[128 * KS];
    __shared__ unsigned short lBhi[128 * KS];
    __shared__ unsigned short lBlo[128 * KS];
    __shared__ float smax[128][2];
    __shared__ float ssum[128][2];

    const int isbf = detect_bf16(X);
    const int t    = threadIdx.x;
    // XCD-aware swizzle (grid 32x32, nwg=1024): each XCD owns a 4-row-tile panel;
    // within it bx sweeps fastest -> QW panel (2MB hi+lo) stays L2-hot.
    const int lid  = blockIdx.y * 32 + blockIdx.x;
    const int swz  = (lid & 7) * 128 + (lid >> 3);
    const int bx   = swz & 31;   // col tile
    const int by   = swz >> 5;   // row tile
    const int lane = t & 63;
    const int w    = t >> 6;
    const int wr   = w >> 1;
    const int wc   = w & 1;
    const int fr   = lane & 15;
    const int fq   = lane >> 4;

    f32x4 acc[4][4];
    #pragma unroll
    for (int i = 0; i < 4; i++)
        #pragma unroll
        for (int j = 0; j < 4; j++)
            acc[i][j] = (f32x4){0.f, 0.f, 0.f, 0.f};

    const int trow = t >> 2;
    const int tcs  = t & 3;

    for (int kt = 0; kt < DM; kt += KS) {
        #pragma unroll
        for (int p = 0; p < 2; p++) {
            const int row = p * 64 + trow;
            const int sc  = tcs ^ ((row >> 1) & 3);
            const int lof = (p * 256 + t) * 16;
            const size_t ga = (size_t)(by * BM + row) * DM + kt + sc * 8;
            gl16(QWhi + ga, (char*)lAhi + lof);
            gl16(QWlo + ga, (char*)lAlo + lof);
            if (isbf) {
                const size_t gb = (size_t)(bx * BN + row) * DM + kt + sc * 8;
                gl16((const unsigned short*)X + gb, (char*)lBhi + lof);
            }
        }
        if (!isbf) {
            const int row  = t >> 1;
            const int half = t & 1;
            const float* xp = (const float*)X + (size_t)(bx * BN + row) * DM + kt + half * 16;
            float4 v0 = ((const float4*)xp)[0];
            float4 v1 = ((const float4*)xp)[1];
            float4 v2 = ((const float4*)xp)[2];
            float4 v3 = ((const float4*)xp)[3];
            float vv[16] = {v0.x, v0.y, v0.z, v0.w, v1.x, v1.y, v1.z, v1.w,
                            v2.x, v2.y, v2.z, v2.w, v3.x, v3.y, v3.z, v3.w};
            U4 h0, h1, l0, l1;
            #pragma unroll
            for (int q = 0; q < 8; q++) {
                h0.s[q] = f2bf(vv[q]);
                l0.s[q] = f2bf(vv[q] - bf2f(h0.s[q]));
                h1.s[q] = f2bf(vv[8 + q]);
                l1.s[q] = f2bf(vv[8 + q] - bf2f(h1.s[q]));
            }
            const int s  = (row >> 1) & 3;
            const int ca = (2 * half) ^ s;
            const int cb = (2 * half + 1) ^ s;
            *(uint4*)&lBhi[row * KS + ca * 8] = h0.u;
            *(uint4*)&lBhi[row * KS + cb * 8] = h1.u;
            *(uint4*)&lBlo[row * KS + ca * 8] = l0.u;
            *(uint4*)&lBlo[row * KS + cb * 8] = l1.u;
        }
        __syncthreads();

        bf16x8 bh[4];
        #pragma unroll
        for (int nj = 0; nj < 4; nj++) {
            const int br = wc * 64 + nj * 16 + fr;
            const int bc = fq ^ ((br >> 1) & 3);
            bh[nj] = *(const bf16x8*)&lBhi[br * KS + bc * 8];
        }
        #pragma unroll
        for (int mi = 0; mi < 4; mi++) {
            const int ar_ = wr * 64 + mi * 16 + fr;
            const int ac_ = fq ^ ((ar_ >> 1) & 3);
            bf16x8 ah = *(const bf16x8*)&lAhi[ar_ * KS + ac_ * 8];
            bf16x8 al = *(const bf16x8*)&lAlo[ar_ * KS + ac_ * 8];
            #pragma unroll
            for (int nj = 0; nj < 4; nj++) {
                acc[mi][nj] = __builtin_amdgcn_mfma_f32_16x16x32_bf16(ah, bh[nj], acc[mi][nj], 0, 0, 0);
                acc[mi][nj] = __builtin_amdgcn_mfma_f32_16x16x32_bf16(al, bh[nj], acc[mi][nj], 0, 0, 0);
            }
        }
        if (!isbf) {
            bf16x8 bl[4];
            #pragma unroll
            for (int nj = 0; nj < 4; nj++) {
                const int br = wc * 64 + nj * 16 + fr;
                const int bc = fq ^ ((br >> 1) & 3);
                bl[nj] = *(const bf16x8*)&lBlo[br * KS + bc * 8];
            }
            #pragma unroll
            for (int mi = 0; mi < 4; mi++) {
                const int ar_ = wr * 64 + mi * 16 + fr;
                const int ac_ = fq ^ ((ar_ >> 1) & 3);
                bf16x8 ah = *(const bf16x8*)&lAhi[ar_ * KS + ac_ * 8];
                #pragma unroll
                for (int nj = 0; nj < 4; nj++)
                    acc[mi][nj] = __builtin_amdgcn_mfma_f32_16x16x32_bf16(ah, bl[nj], acc[mi][nj], 0, 0, 0);
            }
        }
        __syncthreads();
    }

    // ---- fused softmax epilogue ----
    float rmx[4][4];
    #pragma unroll
    for (int mi = 0; mi < 4; mi++)
        #pragma unroll
        for (int reg = 0; reg < 4; reg++) {
            float m = acc[mi][0][reg];
            #pragma unroll
            for (int nj = 1; nj < 4; nj++) m = fmaxf(m, acc[mi][nj][reg]);
            m = fmaxf(m, __shfl_xor(m, 1, 64));
            m = fmaxf(m, __shfl_xor(m, 2, 64));
            m = fmaxf(m, __shfl_xor(m, 4, 64));
            m = fmaxf(m, __shfl_xor(m, 8, 64));
            rmx[mi][reg] = m;
        }
    if (fr == 0) {
        #pragma unroll
        for (int mi = 0; mi < 4; mi++)
            #pragma unroll
            for (int reg = 0; reg < 4; reg++)
                smax[wr * 64 + mi * 16 + fq * 4 + reg][wc] = rmx[mi][reg];
    }
    __syncthreads();
    float mt[4][4];
    #pragma unroll
    for (int mi = 0; mi < 4; mi++)
        #pragma unroll
        for (int reg = 0; reg < 4; reg++) {
            const int r = wr * 64 + mi * 16 + fq * 4 + reg;
            mt[mi][reg] = fmaxf(smax[r][0], smax[r][1]);
        }
    float rsm[4][4];
    #pragma unroll
    for (int mi = 0; mi < 4; mi++)
        #pragma unroll
        for (int reg = 0; reg < 4; reg++) rsm[mi][reg] = 0.f;
    #pragma unroll
    for (int mi = 0; mi < 4; mi++)
        #pragma unroll
        for (int nj = 0; nj < 4; nj++)
            #pragma unroll
            for (int reg = 0; reg < 4; reg++) {
                float e = __expf(acc[mi][nj][reg] - mt[mi][reg]);
                acc[mi][nj][reg] = e;
                rsm[mi][reg] += e;
            }
    #pragma unroll
    for (int mi = 0; mi < 4; mi++)
        #pragma unroll
        for (int reg = 0; reg < 4; reg++) {
            float s = rsm[mi][reg];
            s += __shfl_xor(s, 1, 64);
            s += __shfl_xor(s, 2, 64);
            s += __shfl_xor(s, 4, 64);
            s += __shfl_xor(s, 8, 64);
            if (fr == 0) ssum[wr * 64 + mi * 16 + fq * 4 + reg][wc] = s;
        }
    #pragma unroll
    for (int mi = 0; mi < 4; mi++)
        #pragma unroll
        for (int reg = 0; reg < 4; reg++) {
            const int row = by * BM + wr * 64 + mi * 16 + fq * 4 + reg;
            #pragma unroll
            for (int nj = 0; nj < 4; nj++) {
                const int col = bx * BN + wc * 64 + nj * 16 + fr;
                const float v = acc[mi][nj][reg];
                if (isbf)
                    ((unsigned short*)out)[(size_t)row * SEQ + col] = f2bf(v);
                else
                    ((float*)out)[(size_t)row * SEQ + col] = v;
            }
        }
    __syncthreads();
    if (t < 128) {
        const int grow = by * BM + t;
        pm[(size_t)bx * SEQ + grow] = fmaxf(smax[t][0], smax[t][1]);
        pl[(size_t)bx * SEQ + grow] = ssum[t][0] + ssum[t][1];
    }
}

// ---------------- global reduce: m,l per row -> per-(tile,row) factor exp(m_t - m)/l
__global__ __launch_bounds__(256)
void reduce_kernel(const float* __restrict__ pm, float* __restrict__ pl)
{
    int r = blockIdx.x * 256 + threadIdx.x;
    if (r >= SEQ) return;
    float m = pm[r];
    #pragma unroll
    for (int ti = 1; ti < NCT; ti++) m = fmaxf(m, pm[(size_t)ti * SEQ + r]);
    float l = 0.f;
    #pragma unroll
    for (int ti = 0; ti < NCT; ti++)
        l += pl[(size_t)ti * SEQ + r] * __expf(pm[(size_t)ti * SEQ + r] - m);
    float il = 1.f / l;
    #pragma unroll
    for (int ti = 0; ti < NCT; ti++)
        pl[(size_t)ti * SEQ + r] = __expf(pm[(size_t)ti * SEQ + r] - m) * il;
}

// ---------------- fixup: out *= factor[tile][row]
__global__ __launch_bounds__(256)
void fixup_kernel(const float* __restrict__ F, const void* __restrict__ X,
                  void* __restrict__ out)
{
    const int isbf = detect_bf16(X);
    size_t g = ((size_t)blockIdx.x * 256 + threadIdx.x) * 8;
    const int row = (int)(g >> 12);
    const int col = (int)(g & (SEQ - 1));
    const float f = F[(size_t)(col >> 7) * SEQ + row];
    if (isbf) {
        unsigned short* p = (unsigned short*)out + g;
        U4 v; v.u = *(const uint4*)p;
        #pragma unroll
        for (int q = 0; q < 8; q++) v.s[q] = f2bf(bf2f(v.s[q]) * f);
        *(uint4*)p = v.u;
    } else {
        float* p = (float*)out + g;
        float4 a = *(const float4*)p;
        float4 b = *(const float4*)(p + 4);
        a.x *= f; a.y *= f; a.z *= f; a.w *= f;
        b.x *= f; b.y *= f; b.z *= f; b.w *= f;
        *(float4*)p = a;
        *(float4*)(p + 4) = b;
    }
}

extern "C" void kernel_launch(void* const* d_in, const int* in_sizes, int n_in,
                              void* d_out, int out_size, void* d_ws, size_t ws_size,
                              hipStream_t stream)
{
    const void* x  = d_in[0];
    const void* wq = d_in[1];
    const void* wk = d_in[2];
    // d_in[3] (w_v), d_in[4] (out_proj) unused by the reference output.

    // Buffer timeline (ws = 32 MiB, d_out = 64 MiB scratch until scores):
    //   phase          ws[0,8M)  ws[8,16M)  ws[16,20M)   ws[16,17M)  d_out
    //   1 split3       Xhi<-     Xlo<-      -            -           W splits<- [0,8M)
    //   2 w2t mfma     (Xhi)     (Xlo)      -            -           ->W reads; W2P<- [8,24M)
    //   3 w2_red_split (Xhi)     (Xlo)      W2Thi/lo<-   -           ->W2P read
    //   4 qw mfma      ->read    ->read     ->read       -           QP0/QP1<- [24,56M)
    //   5 qw_combine   QWhi<-    QWlo<-     -            -           ->QP read
    //   6 scores       ->read    ->read     (dead)       pm/pl<-     P<- [0,64M)
    //   7 reduce/fixup -         -          -            pm/pl r/w   P r/w
    // All same-phase read/write regions are disjoint; cross-phase ordering is
    // stream-sequential.
    char* wsb = (char*)d_ws;
    char* dob = (char*)d_out;
    unsigned short* Xhi   = (unsigned short*)wsb;
    unsigned short* Xlo   = (unsigned short*)(wsb + ((size_t)8 << 20));
    unsigned short* QWhi  = (unsigned short*)wsb;                       // over dead Xhi
    unsigned short* QWlo  = (unsigned short*)(wsb + ((size_t)8 << 20)); // over dead Xlo
    unsigned short* W2Thi = (unsigned short*)(wsb + ((size_t)16 << 20));
    unsigned short* W2Tlo = (unsigned short*)(wsb + ((size_t)18 << 20));
    float*          pm    = (float*)(wsb + ((size_t)16 << 20));         // over dead W2T
    float*          pl    = pm + (size_t)NCT * SEQ;

    unsigned short* Wkhi = (unsigned short*)dob;
    unsigned short* Wklo = (unsigned short*)(dob + ((size_t)2 << 20));
    unsigned short* Wqhi = (unsigned short*)(dob + ((size_t)4 << 20));
    unsigned short* Wqlo = (unsigned short*)(dob + ((size_t)6 << 20));
    float*          W2P  = (float*)(dob + ((size_t)8 << 20));   // 4 x 4MB partials
    float*          QP0  = (float*)(dob + ((size_t)24 << 20));  // 16MB
    float*          QP1  = QP0 + (size_t)SEQ * DM;              // 16MB

    dim3 blk(256);
    // 1. x, wq, wk -> bf16 hi/lo splits (one pass)
    split3_kernel<<<dim3(3072), blk, 0, stream>>>(x, wq, wk, Xhi, Xlo, Wqhi, Wqlo, Wkhi, Wklo);
    // 2. W2T = (1/32) * wk @ wq^T via 4-term split MFMA, split-K=4 (grid 8x8x4)
    part_mfma_kernel<<<dim3(8, DM / BM, 4), blk, 0, stream>>>(
        Wkhi, Wklo, Wqhi, Wqlo, W2P, DM / 4, (size_t)DM * DM, 0.03125f);
    // 3. sum partials -> W2T bf16 hi/lo
    w2_reduce_split_kernel<<<dim3(DM * DM / (8 * 256)), blk, 0, stream>>>(W2P, W2Thi, W2Tlo);
    // 4. QW = Xs @ W2T^T via 4-term split MFMA, split-K=2 (grid 8x32x2)
    part_mfma_kernel<<<dim3(8, SEQ / BM, 2), blk, 0, stream>>>(
        Xhi, Xlo, W2Thi, W2Tlo, QP0, DM / 2, (size_t)SEQ * DM, 1.0f);
    // 5. QW partial sum -> bf16 hi/lo
    qw_combine_split_kernel<<<dim3(SEQ * DM / (8 * 256)), blk, 0, stream>>>(QP0, QP1, QWhi, QWlo);
    // 6. scores via MFMA + fused softmax partials, P to d_out
    scores_mfma_kernel<<<dim3(SEQ / BN, SEQ / BM), blk, 0, stream>>>(QWhi, QWlo, x, pm, pl, d_out);
    // 7. per-row global max/sum -> per-(tile,row) factors (into pl)
    reduce_kernel<<<dim3(SEQ / 256), blk, 0, stream>>>(pm, pl);
    // 8. out *= factor
    fixup_kernel<<<dim3(SEQ * SEQ / (8 * 256)), blk, 0, stream>>>(pl, x, d_out);
}

// Round 5
// 304.299 us; speedup vs baseline: 4.0545x; 1.0054x over previous
//
#include <hip/hip_runtime.h>
#include <math.h>

#define SEQ 4096
#define DM  1024

#define BM 128
#define BN 128
#define NCT (SEQ / BN)   // 32 column tiles
#define KS 32            // K per MFMA step

typedef __attribute__((ext_vector_type(8))) short bf16x8;
typedef __attribute__((ext_vector_type(4))) float f32x4;

union U4 { uint4 u; unsigned short s[8]; };

__device__ __forceinline__ float bf2f(unsigned short u) {
    return __uint_as_float(((unsigned int)u) << 16);
}
__device__ __forceinline__ unsigned short f2bf(float f) {
    unsigned int u = __float_as_uint(f);
    return (unsigned short)((u + 0x7FFFu + ((u >> 16) & 1u)) >> 16);
}

// Decide whether buffer holds packed bf16 (1) or fp32 (0).
__device__ __forceinline__ int detect_bf16(const void* p0) {
    const unsigned int* p = (const unsigned int*)p0;
    int cnt = 0;
    #pragma unroll
    for (int i = 0; i < 64; i++) {
        unsigned int e = (p[i] >> 7) & 0xFFu;
        cnt += (e >= 112u && e <= 140u) ? 1 : 0;
    }
    return cnt >= 48 ? 1 : 0;
}

// load 8 consecutive elements (element index idx, multiple of 8) as fp32
__device__ __forceinline__ void load8(const void* base, size_t idx, int isbf, float* v) {
    if (isbf) {
        U4 t; t.u = *(const uint4*)((const unsigned short*)base + idx);
        #pragma unroll
        for (int q = 0; q < 8; q++) v[q] = bf2f(t.s[q]);
    } else {
        const float* f = (const float*)base + idx;
        float4 a = *(const float4*)f;
        float4 b = *(const float4*)(f + 4);
        v[0] = a.x; v[1] = a.y; v[2] = a.z; v[3] = a.w;
        v[4] = b.x; v[5] = b.y; v[6] = b.z; v[7] = b.w;
    }
}

// async global -> LDS, 16 bytes per lane (linear LDS dest: base + lane*16)
__device__ __forceinline__ void gl16(const void* g, void* l) {
    __builtin_amdgcn_global_load_lds(
        (const __attribute__((address_space(1))) unsigned int*)g,
        (__attribute__((address_space(3))) unsigned int*)l, 16, 0, 0);
}

// ---------------- split3: x / wq / wk -> exact bf16 hi/lo pairs, one pass.
// blocks [0,2048): x (4M elems); [2048,2560): wq (1M); [2560,3072): wk (1M)
__global__ __launch_bounds__(256)
void split3_kernel(const void* __restrict__ X, const void* __restrict__ Wq,
                   const void* __restrict__ Wk,
                   unsigned short* __restrict__ Xhi, unsigned short* __restrict__ Xlo,
                   unsigned short* __restrict__ Wqhi, unsigned short* __restrict__ Wqlo,
                   unsigned short* __restrict__ Wkhi, unsigned short* __restrict__ Wklo)
{
    const int b = blockIdx.x;
    const void* src;
    unsigned short *Hi, *Lo;
    size_t i;
    if (b < 2048)      { src = X;  Hi = Xhi;  Lo = Xlo;  i = ((size_t)b * 256 + threadIdx.x) * 8; }
    else if (b < 2560) { src = Wq; Hi = Wqhi; Lo = Wqlo; i = ((size_t)(b - 2048) * 256 + threadIdx.x) * 8; }
    else               { src = Wk; Hi = Wkhi; Lo = Wklo; i = ((size_t)(b - 2560) * 256 + threadIdx.x) * 8; }
    const int isbf = detect_bf16(src);
    float v[8];
    load8(src, i, isbf, v);
    U4 h, l;
    #pragma unroll
    for (int q = 0; q < 8; q++) {
        h.s[q] = f2bf(v[q]);
        l.s[q] = f2bf(v[q] - bf2f(h.s[q]));
    }
    *(uint4*)(Hi + i) = h.u;
    *(uint4*)(Lo + i) = l.u;
}

// ---------------- generic NT split-bf16 MFMA partial GEMM (3-term):
// O[kz*pstride + m*DM + n] = scale * sum_{k in chunk kz} A[m,k]*B[n,k]
// A = Ahi+Alo, B = Bhi+Blo (exact splits). Terms ah*bh + al*bh + ah*bl;
// the al*bl term (<=2^-18 rel) is dropped -> ~1e-3 score-level error, negligible.
// 128x128 tile, 4 waves, KS=32, XOR-swizzled-source gl16 staging (linear LDS dest).
// Grid (8, M/128, KZ) with bijective XCD swizzle (nwg % 8 == 0 in both uses).
__global__ __launch_bounds__(256)
void part_mfma_kernel(const unsigned short* __restrict__ Ahi, const unsigned short* __restrict__ Alo,
                      const unsigned short* __restrict__ Bhi, const unsigned short* __restrict__ Blo,
                      float* __restrict__ O, int kchunk, size_t pstride, float scale)
{
    __shared__ unsigned short lAhi[128 * KS];
    __shared__ unsigned short lAlo[128 * KS];
    __shared__ unsigned short lBhi[128 * KS];
    __shared__ unsigned short lBlo[128 * KS];

    const int t = threadIdx.x;
    // XCD-aware bijective remap (T1)
    const int gy  = gridDim.y;
    const int nwg = 8 * gy * gridDim.z;
    const int lid = (blockIdx.z * gy + blockIdx.y) * 8 + blockIdx.x;
    const int swz = (lid & 7) * (nwg >> 3) + (lid >> 3);
    const int bx  = swz & 7;
    const int rst = swz >> 3;
    const int by  = rst % gy;
    const int kz  = rst / gy;

    const int lane = t & 63;
    const int w    = t >> 6;
    const int wr   = w >> 1;
    const int wc   = w & 1;
    const int fr   = lane & 15;
    const int fq   = lane >> 4;

    f32x4 acc[4][4];
    #pragma unroll
    for (int i = 0; i < 4; i++)
        #pragma unroll
        for (int j = 0; j < 4; j++)
            acc[i][j] = (f32x4){0.f, 0.f, 0.f, 0.f};

    const int trow = t >> 2;
    const int tcs  = t & 3;
    const int k0   = kz * kchunk;

    for (int kt = k0; kt < k0 + kchunk; kt += KS) {
        #pragma unroll
        for (int p = 0; p < 2; p++) {
            const int row = p * 64 + trow;
            const int sc  = tcs ^ ((row >> 1) & 3);
            const int lof = (p * 256 + t) * 16;
            const size_t ga = (size_t)(by * BM + row) * DM + kt + sc * 8;
            const size_t gb = (size_t)(bx * BN + row) * DM + kt + sc * 8;
            gl16(Ahi + ga, (char*)lAhi + lof);
            gl16(Alo + ga, (char*)lAlo + lof);
            gl16(Bhi + gb, (char*)lBhi + lof);
            gl16(Blo + gb, (char*)lBlo + lof);
        }
        __syncthreads();

        bf16x8 bh[4], bl[4];
        #pragma unroll
        for (int nj = 0; nj < 4; nj++) {
            const int br = wc * 64 + nj * 16 + fr;
            const int bc = fq ^ ((br >> 1) & 3);
            bh[nj] = *(const bf16x8*)&lBhi[br * KS + bc * 8];
            bl[nj] = *(const bf16x8*)&lBlo[br * KS + bc * 8];
        }
        #pragma unroll
        for (int mi = 0; mi < 4; mi++) {
            const int ar_ = wr * 64 + mi * 16 + fr;
            const int ac_ = fq ^ ((ar_ >> 1) & 3);
            bf16x8 ah = *(const bf16x8*)&lAhi[ar_ * KS + ac_ * 8];
            bf16x8 al = *(const bf16x8*)&lAlo[ar_ * KS + ac_ * 8];
            #pragma unroll
            for (int nj = 0; nj < 4; nj++) {
                acc[mi][nj] = __builtin_amdgcn_mfma_f32_16x16x32_bf16(ah, bh[nj], acc[mi][nj], 0, 0, 0);
                acc[mi][nj] = __builtin_amdgcn_mfma_f32_16x16x32_bf16(al, bh[nj], acc[mi][nj], 0, 0, 0);
                acc[mi][nj] = __builtin_amdgcn_mfma_f32_16x16x32_bf16(ah, bl[nj], acc[mi][nj], 0, 0, 0);
            }
        }
        __syncthreads();
    }

    float* Op = O + (size_t)kz * pstride;
    #pragma unroll
    for (int mi = 0; mi < 4; mi++)
        #pragma unroll
        for (int reg = 0; reg < 4; reg++) {
            const int row = by * BM + wr * 64 + mi * 16 + fq * 4 + reg;
            #pragma unroll
            for (int nj = 0; nj < 4; nj++) {
                const int col = bx * BN + wc * 64 + nj * 16 + fr;
                Op[(size_t)row * DM + col] = acc[mi][nj][reg] * scale;
            }
        }
}

// ---------------- W2T = sum of 4 K-chunk partials -> bf16 hi/lo split
__global__ __launch_bounds__(256)
void w2_reduce_split_kernel(const float* __restrict__ P, unsigned short* __restrict__ Hi,
                            unsigned short* __restrict__ Lo)
{
    const size_t N = (size_t)DM * DM;
    size_t i = ((size_t)blockIdx.x * 256 + threadIdx.x) * 8;
    float v[8];
    #pragma unroll
    for (int h = 0; h < 8; h += 4) {
        float4 a = *(const float4*)(P + i + h);
        float4 b = *(const float4*)(P + N + i + h);
        float4 c = *(const float4*)(P + 2 * N + i + h);
        float4 d = *(const float4*)(P + 3 * N + i + h);
        v[h + 0] = a.x + b.x + c.x + d.x;
        v[h + 1] = a.y + b.y + c.y + d.y;
        v[h + 2] = a.z + b.z + c.z + d.z;
        v[h + 3] = a.w + b.w + c.w + d.w;
    }
    U4 h, l;
    #pragma unroll
    for (int q = 0; q < 8; q++) {
        h.s[q] = f2bf(v[q]);
        l.s[q] = f2bf(v[q] - bf2f(h.s[q]));
    }
    *(uint4*)(Hi + i) = h.u;
    *(uint4*)(Lo + i) = l.u;
}

// ---------------- QW = P0 + P1, split into bf16 hi/lo pair (for scores A operand)
__global__ __launch_bounds__(256)
void qw_combine_split_kernel(const float* __restrict__ P0, const float* __restrict__ P1,
                             unsigned short* __restrict__ Hi, unsigned short* __restrict__ Lo)
{
    size_t i = ((size_t)blockIdx.x * 256 + threadIdx.x) * 8;
    float4 a0 = *(const float4*)(P0 + i);
    float4 a1 = *(const float4*)(P0 + i + 4);
    float4 b0 = *(const float4*)(P1 + i);
    float4 b1 = *(const float4*)(P1 + i + 4);
    float v[8] = {a0.x + b0.x, a0.y + b0.y, a0.z + b0.z, a0.w + b0.w,
                  a1.x + b1.x, a1.y + b1.y, a1.z + b1.z, a1.w + b1.w};
    U4 h, l;
    #pragma unroll
    for (int q = 0; q < 8; q++) {
        h.s[q] = f2bf(v[q]);
        l.s[q] = f2bf(v[q] - bf2f(h.s[q]));
    }
    *(uint4*)(Hi + i) = h.u;
    *(uint4*)(Lo + i) = l.u;
}

// ---------------- scores via MFMA: S = (QWhi+QWlo) @ X^T, fused softmax partials.
// No XCD swizzle: measured (r4 vs r3) the swizzle raised FETCH 82->139 MB, dur flat.
__global__ __launch_bounds__(256)
void scores_mfma_kernel(const unsigned short* __restrict__ QWhi,
                        const unsigned short* __restrict__ QWlo,
                        const void* __restrict__ X,
                        float* __restrict__ pm, float* __restrict__ pl,
                        void* __restrict__ out)
{
    __shared__ unsigned short lAhi[128 * KS];
    __shared__ unsigned short lAlo[128 * KS];
    __shared__ unsigned short lBhi[128 * KS];
    __shared__ unsigned short lBlo[128 * KS];
    __shared__ float smax[128][2];
    __shared__ float ssum[128][2];

    const int isbf = detect_bf16(X);
    const int t    = threadIdx.x;
    const int bx   = blockIdx.x;   // col tile
    const int by   = blockIdx.y;   // row tile
    const int lane = t & 63;
    const int w    = t >> 6;
    const int wr   = w >> 1;
    const int wc   = w & 1;
    const int fr   = lane & 15;
    const int fq   = lane >> 4;

    f32x4 acc[4][4];
    #pragma unroll
    for (int i = 0; i < 4; i++)
        #pragma unroll
        for (int j = 0; j < 4; j++)
            acc[i][j] = (f32x4){0.f, 0.f, 0.f, 0.f};

    const int trow = t >> 2;
    const int tcs  = t & 3;

    for (int kt = 0; kt < DM; kt += KS) {
        #pragma unroll
        for (int p = 0; p < 2; p++) {
            const int row = p * 64 + trow;
            const int sc  = tcs ^ ((row >> 1) & 3);
            const int lof = (p * 256 + t) * 16;
            const size_t ga = (size_t)(by * BM + row) * DM + kt + sc * 8;
            gl16(QWhi + ga, (char*)lAhi + lof);
            gl16(QWlo + ga, (char*)lAlo + lof);
            if (isbf) {
                const size_t gb = (size_t)(bx * BN + row) * DM + kt + sc * 8;
                gl16((const unsigned short*)X + gb, (char*)lBhi + lof);
            }
        }
        if (!isbf) {
            const int row  = t >> 1;
            const int half = t & 1;
            const float* xp = (const float*)X + (size_t)(bx * BN + row) * DM + kt + half * 16;
            float4 v0 = ((const float4*)xp)[0];
            float4 v1 = ((const float4*)xp)[1];
            float4 v2 = ((const float4*)xp)[2];
            float4 v3 = ((const float4*)xp)[3];
            float vv[16] = {v0.x, v0.y, v0.z, v0.w, v1.x, v1.y, v1.z, v1.w,
                            v2.x, v2.y, v2.z, v2.w, v3.x, v3.y, v3.z, v3.w};
            U4 h0, h1, l0, l1;
            #pragma unroll
            for (int q = 0; q < 8; q++) {
                h0.s[q] = f2bf(vv[q]);
                l0.s[q] = f2bf(vv[q] - bf2f(h0.s[q]));
                h1.s[q] = f2bf(vv[8 + q]);
                l1.s[q] = f2bf(vv[8 + q] - bf2f(h1.s[q]));
            }
            const int s  = (row >> 1) & 3;
            const int ca = (2 * half) ^ s;
            const int cb = (2 * half + 1) ^ s;
            *(uint4*)&lBhi[row * KS + ca * 8] = h0.u;
            *(uint4*)&lBhi[row * KS + cb * 8] = h1.u;
            *(uint4*)&lBlo[row * KS + ca * 8] = l0.u;
            *(uint4*)&lBlo[row * KS + cb * 8] = l1.u;
        }
        __syncthreads();

        bf16x8 bh[4];
        #pragma unroll
        for (int nj = 0; nj < 4; nj++) {
            const int br = wc * 64 + nj * 16 + fr;
            const int bc = fq ^ ((br >> 1) & 3);
            bh[nj] = *(const bf16x8*)&lBhi[br * KS + bc * 8];
        }
        #pragma unroll
        for (int mi = 0; mi < 4; mi++) {
            const int ar_ = wr * 64 + mi * 16 + fr;
            const int ac_ = fq ^ ((ar_ >> 1) & 3);
            bf16x8 ah = *(const bf16x8*)&lAhi[ar_ * KS + ac_ * 8];
            bf16x8 al = *(const bf16x8*)&lAlo[ar_ * KS + ac_ * 8];
            #pragma unroll
            for (int nj = 0; nj < 4; nj++) {
                acc[mi][nj] = __builtin_amdgcn_mfma_f32_16x16x32_bf16(ah, bh[nj], acc[mi][nj], 0, 0, 0);
                acc[mi][nj] = __builtin_amdgcn_mfma_f32_16x16x32_bf16(al, bh[nj], acc[mi][nj], 0, 0, 0);
            }
        }
        if (!isbf) {
            bf16x8 bl[4];
            #pragma unroll
            for (int nj = 0; nj < 4; nj++) {
                const int br = wc * 64 + nj * 16 + fr;
                const int bc = fq ^ ((br >> 1) & 3);
                bl[nj] = *(const bf16x8*)&lBlo[br * KS + bc * 8];
            }
            #pragma unroll
            for (int mi = 0; mi < 4; mi++) {
                const int ar_ = wr * 64 + mi * 16 + fr;
                const int ac_ = fq ^ ((ar_ >> 1) & 3);
                bf16x8 ah = *(const bf16x8*)&lAhi[ar_ * KS + ac_ * 8];
                #pragma unroll
                for (int nj = 0; nj < 4; nj++)
                    acc[mi][nj] = __builtin_amdgcn_mfma_f32_16x16x32_bf16(ah, bl[nj], acc[mi][nj], 0, 0, 0);
            }
        }
        __syncthreads();
    }

    // ---- fused softmax epilogue ----
    float rmx[4][4];
    #pragma unroll
    for (int mi = 0; mi < 4; mi++)
        #pragma unroll
        for (int reg = 0; reg < 4; reg++) {
            float m = acc[mi][0][reg];
            #pragma unroll
            for (int nj = 1; nj < 4; nj++) m = fmaxf(m, acc[mi][nj][reg]);
            m = fmaxf(m, __shfl_xor(m, 1, 64));
            m = fmaxf(m, __shfl_xor(m, 2, 64));
            m = fmaxf(m, __shfl_xor(m, 4, 64));
            m = fmaxf(m, __shfl_xor(m, 8, 64));
            rmx[mi][reg] = m;
        }
    if (fr == 0) {
        #pragma unroll
        for (int mi = 0; mi < 4; mi++)
            #pragma unroll
            for (int reg = 0; reg < 4; reg++)
                smax[wr * 64 + mi * 16 + fq * 4 + reg][wc] = rmx[mi][reg];
    }
    __syncthreads();
    float mt[4][4];
    #pragma unroll
    for (int mi = 0; mi < 4; mi++)
        #pragma unroll
        for (int reg = 0; reg < 4; reg++) {
            const int r = wr * 64 + mi * 16 + fq * 4 + reg;
            mt[mi][reg] = fmaxf(smax[r][0], smax[r][1]);
        }
    float rsm[4][4];
    #pragma unroll
    for (int mi = 0; mi < 4; mi++)
        #pragma unroll
        for (int reg = 0; reg < 4; reg++) rsm[mi][reg] = 0.f;
    #pragma unroll
    for (int mi = 0; mi < 4; mi++)
        #pragma unroll
        for (int nj = 0; nj < 4; nj++)
            #pragma unroll
            for (int reg = 0; reg < 4; reg++) {
                float e = __expf(acc[mi][nj][reg] - mt[mi][reg]);
                acc[mi][nj][reg] = e;
                rsm[mi][reg] += e;
            }
    #pragma unroll
    for (int mi = 0; mi < 4; mi++)
        #pragma unroll
        for (int reg = 0; reg < 4; reg++) {
            float s = rsm[mi][reg];
            s += __shfl_xor(s, 1, 64);
            s += __shfl_xor(s, 2, 64);
            s += __shfl_xor(s, 4, 64);
            s += __shfl_xor(s, 8, 64);
            if (fr == 0) ssum[wr * 64 + mi * 16 + fq * 4 + reg][wc] = s;
        }
    #pragma unroll
    for (int mi = 0; mi < 4; mi++)
        #pragma unroll
        for (int reg = 0; reg < 4; reg++) {
            const int row = by * BM + wr * 64 + mi * 16 + fq * 4 + reg;
            #pragma unroll
            for (int nj = 0; nj < 4; nj++) {
                const int col = bx * BN + wc * 64 + nj * 16 + fr;
                const float v = acc[mi][nj][reg];
                if (isbf)
                    ((unsigned short*)out)[(size_t)row * SEQ + col] = f2bf(v);
                else
                    ((float*)out)[(size_t)row * SEQ + col] = v;
            }
        }
    __syncthreads();
    if (t < 128) {
        const int grow = by * BM + t;
        pm[(size_t)bx * SEQ + grow] = fmaxf(smax[t][0], smax[t][1]);
        pl[(size_t)bx * SEQ + grow] = ssum[t][0] + ssum[t][1];
    }
}

// ---------------- global reduce: m,l per row -> per-(tile,row) factor exp(m_t - m)/l
__global__ __launch_bounds__(256)
void reduce_kernel(const float* __restrict__ pm, float* __restrict__ pl)
{
    int r = blockIdx.x * 256 + threadIdx.x;
    if (r >= SEQ) return;
    float m = pm[r];
    #pragma unroll
    for (int ti = 1; ti < NCT; ti++) m = fmaxf(m, pm[(size_t)ti * SEQ + r]);
    float l = 0.f;
    #pragma unroll
    for (int ti = 0; ti < NCT; ti++)
        l += pl[(size_t)ti * SEQ + r] * __expf(pm[(size_t)ti * SEQ + r] - m);
    float il = 1.f / l;
    #pragma unroll
    for (int ti = 0; ti < NCT; ti++)
        pl[(size_t)ti * SEQ + r] = __expf(pm[(size_t)ti * SEQ + r] - m) * il;
}

// ---------------- fixup: out *= factor[tile][row]
__global__ __launch_bounds__(256)
void fixup_kernel(const float* __restrict__ F, const void* __restrict__ X,
                  void* __restrict__ out)
{
    const int isbf = detect_bf16(X);
    size_t g = ((size_t)blockIdx.x * 256 + threadIdx.x) * 8;
    const int row = (int)(g >> 12);
    const int col = (int)(g & (SEQ - 1));
    const float f = F[(size_t)(col >> 7) * SEQ + row];
    if (isbf) {
        unsigned short* p = (unsigned short*)out + g;
        U4 v; v.u = *(const uint4*)p;
        #pragma unroll
        for (int q = 0; q < 8; q++) v.s[q] = f2bf(bf2f(v.s[q]) * f);
        *(uint4*)p = v.u;
    } else {
        float* p = (float*)out + g;
        float4 a = *(const float4*)p;
        float4 b = *(const float4*)(p + 4);
        a.x *= f; a.y *= f; a.z *= f; a.w *= f;
        b.x *= f; b.y *= f; b.z *= f; b.w *= f;
        *(float4*)p = a;
        *(float4*)(p + 4) = b;
    }
}

extern "C" void kernel_launch(void* const* d_in, const int* in_sizes, int n_in,
                              void* d_out, int out_size, void* d_ws, size_t ws_size,
                              hipStream_t stream)
{
    const void* x  = d_in[0];
    const void* wq = d_in[1];
    const void* wk = d_in[2];
    // d_in[3] (w_v), d_in[4] (out_proj) unused by the reference output.

    // Buffer timeline (ws = 32 MiB, d_out = 64 MiB scratch until scores):
    //   phase          ws[0,8M)  ws[8,16M)  ws[16,20M)   ws[16,17M)  d_out
    //   1 split3       Xhi<-     Xlo<-      -            -           W splits<- [0,8M)
    //   2 w2t mfma     (Xhi)     (Xlo)      -            -           ->W reads; W2P<- [8,24M)
    //   3 w2_red_split (Xhi)     (Xlo)      W2Thi/lo<-   -           ->W2P read
    //   4 qw mfma      ->read    ->read     ->read       -           QP0/QP1<- [24,56M)
    //   5 qw_combine   QWhi<-    QWlo<-     -            -           ->QP read
    //   6 scores       ->read    ->read     (dead)       pm/pl<-     P<- [0,64M)
    //   7 reduce/fixup -         -          -            pm/pl r/w   P r/w
    char* wsb = (char*)d_ws;
    char* dob = (char*)d_out;
    unsigned short* Xhi   = (unsigned short*)wsb;
    unsigned short* Xlo   = (unsigned short*)(wsb + ((size_t)8 << 20));
    unsigned short* QWhi  = (unsigned short*)wsb;                       // over dead Xhi
    unsigned short* QWlo  = (unsigned short*)(wsb + ((size_t)8 << 20)); // over dead Xlo
    unsigned short* W2Thi = (unsigned short*)(wsb + ((size_t)16 << 20));
    unsigned short* W2Tlo = (unsigned short*)(wsb + ((size_t)18 << 20));
    float*          pm    = (float*)(wsb + ((size_t)16 << 20));         // over dead W2T
    float*          pl    = pm + (size_t)NCT * SEQ;

    unsigned short* Wkhi = (unsigned short*)dob;
    unsigned short* Wklo = (unsigned short*)(dob + ((size_t)2 << 20));
    unsigned short* Wqhi = (unsigned short*)(dob + ((size_t)4 << 20));
    unsigned short* Wqlo = (unsigned short*)(dob + ((size_t)6 << 20));
    float*          W2P  = (float*)(dob + ((size_t)8 << 20));   // 4 x 4MB partials
    float*          QP0  = (float*)(dob + ((size_t)24 << 20));  // 16MB
    float*          QP1  = QP0 + (size_t)SEQ * DM;              // 16MB

    dim3 blk(256);
    // 1. x, wq, wk -> bf16 hi/lo splits (one pass)
    split3_kernel<<<dim3(3072), blk, 0, stream>>>(x, wq, wk, Xhi, Xlo, Wqhi, Wqlo, Wkhi, Wklo);
    // 2. W2T = (1/32) * wk @ wq^T via 3-term split MFMA, split-K=4 (grid 8x8x4)
    part_mfma_kernel<<<dim3(8, DM / BM, 4), blk, 0, stream>>>(
        Wkhi, Wklo, Wqhi, Wqlo, W2P, DM / 4, (size_t)DM * DM, 0.03125f);
    // 3. sum partials -> W2T bf16 hi/lo
    w2_reduce_split_kernel<<<dim3(DM * DM / (8 * 256)), blk, 0, stream>>>(W2P, W2Thi, W2Tlo);
    // 4. QW = Xs @ W2T^T via 3-term split MFMA, split-K=2 (grid 8x32x2)
    part_mfma_kernel<<<dim3(8, SEQ / BM, 2), blk, 0, stream>>>(
        Xhi, Xlo, W2Thi, W2Tlo, QP0, DM / 2, (size_t)SEQ * DM, 1.0f);
    // 5. QW partial sum -> bf16 hi/lo
    qw_combine_split_kernel<<<dim3(SEQ * DM / (8 * 256)), blk, 0, stream>>>(QP0, QP1, QWhi, QWlo);
    // 6. scores via MFMA + fused softmax partials, P to d_out
    scores_mfma_kernel<<<dim3(SEQ / BN, SEQ / BM), blk, 0, stream>>>(QWhi, QWlo, x, pm, pl, d_out);
    // 7. per-row global max/sum -> per-(tile,row) factors (into pl)
    reduce_kernel<<<dim3(SEQ / 256), blk, 0, stream>>>(pm, pl);
    // 8. out *= factor
    fixup_kernel<<<dim3(SEQ * SEQ / (8 * 256)), blk, 0, stream>>>(pl, x, d_out);
}